// Round 12
// baseline (384.263 us; speedup 1.0000x reference)
//
#include <hip/hip_runtime.h>

#define NN 50000
#define NE 800000
#define EP (NE + NN)      // edges + self loops = 850000
#define NG 128
#define F 128
#define NBE 208           // edge-pass blocks
#define EPB 4096          // edges per block (208*4096 >= EP)
#define NBUCK 196         // dst buckets of 256 nodes
#define CMAT (NBUCK * NBE)
#define BCAP 6144         // per-bucket edge cap (mean 4352)

typedef __attribute__((ext_vector_type(8))) short short8;
typedef __attribute__((ext_vector_type(4))) float float4v;
union U8 { uint4 u; short8 s; };

__device__ inline unsigned int bf16rn(float x) {   // RNE round to bf16 (low 16 bits)
    unsigned int u = __float_as_uint(x);
    u += 0x7fffu + ((u >> 16) & 1u);
    return u >> 16;
}
__device__ inline unsigned int pack2(float a, float b) {
    return bf16rn(a) | (bf16rn(b) << 16);
}
// 8 bf16 (uint4) -> 8 fma's into acc[0..7]
__device__ inline void bf8_fma(float* acc, float w, uint4 hv) {
    acc[0] = fmaf(w, __uint_as_float(hv.x << 16), acc[0]);
    acc[1] = fmaf(w, __uint_as_float(hv.x & 0xffff0000u), acc[1]);
    acc[2] = fmaf(w, __uint_as_float(hv.y << 16), acc[2]);
    acc[3] = fmaf(w, __uint_as_float(hv.y & 0xffff0000u), acc[3]);
    acc[4] = fmaf(w, __uint_as_float(hv.z << 16), acc[4]);
    acc[5] = fmaf(w, __uint_as_float(hv.z & 0xffff0000u), acc[5]);
    acc[6] = fmaf(w, __uint_as_float(hv.w << 16), acc[6]);
    acc[7] = fmaf(w, __uint_as_float(hv.w & 0xffff0000u), acc[7]);
}

// fp32 -> bf16 convert, 8 elements/thread
__global__ void cvt_bf16(const float* __restrict__ src, unsigned short* __restrict__ dst,
                         int n8) {
    const int i = blockIdx.x * blockDim.x + threadIdx.x;
    if (i >= n8) return;
    const float4 f0 = *(const float4*)(src + (size_t)i * 8);
    const float4 f1 = *(const float4*)(src + (size_t)i * 8 + 4);
    uint4 pk;
    pk.x = pack2(f0.x, f0.y); pk.y = pack2(f0.z, f0.w);
    pk.z = pack2(f1.x, f1.y); pk.w = pack2(f1.z, f1.w);
    *(uint4*)(dst + (size_t)i * 8) = pk;
}

// One-shot: pack W fp32 [128][128] into MFMA B-fragments (bf16), global image.
// frag f = kt*8+nt, lane l: B[k=kt*32+(l>>4)*8+j][n=nt*16+(l&15)], j=0..7 paired.
__global__ void pack_wfrag(const float* __restrict__ W, uint4* __restrict__ wf) {
    const int p = blockIdx.x * blockDim.x + threadIdx.x;   // 0..2047
    if (p >= 2048) return;
    const int f = p >> 6, l = p & 63;
    const int kt = f >> 3, nt = f & 7;
    const int rb = kt * 32 + ((l >> 4) << 3);
    const int col = nt * 16 + (l & 15);
    const float* wp = W + (size_t)rb * F + col;
    uint4 pk;
    pk.x = pack2(wp[0],     wp[F]);
    pk.y = pack2(wp[2 * F], wp[3 * F]);
    pk.z = pack2(wp[4 * F], wp[5 * F]);
    pk.w = pack2(wp[6 * F], wp[7 * F]);
    wf[p] = pk;
}

// C[N,128] = A[N,128] @ W via v_mfma_f32_16x16x32_bf16. No LDS, no barriers:
// B-fragments pre-packed in global (32 KB, L2-broadcast). 4 waves = 64 rows/block.
// Layouts (verified R11 end-to-end): A[m=l&15][k=(l>>4)*8+j]; C/D row=(l>>4)*4+r, col=l&15.
__global__ __launch_bounds__(256) void mfma_gemm(
        const unsigned short* __restrict__ Ab, const uint4* __restrict__ wf,
        unsigned short* __restrict__ Cb, int N,
        const float* __restrict__ att_src, const float* __restrict__ att_dst,
        float* __restrict__ asrc, float* __restrict__ adst) {
    const int t = threadIdx.x;
    const int wave = t >> 6, lane = t & 63;
    const int m0 = blockIdx.x * 64 + wave * 16;
    const int arow = m0 + (lane & 15);
    const int kq = (lane >> 4) << 3;
    U8 a[4];
#pragma unroll
    for (int kt = 0; kt < 4; ++kt) {
        if (arow < N) a[kt].u = *(const uint4*)(Ab + (size_t)arow * F + kt * 32 + kq);
        else          a[kt].u = make_uint4(0, 0, 0, 0);
    }
    const int ccol = lane & 15;
    const int crow0 = m0 + ((lane >> 4) << 2);
    float ps[4] = {}, pd[4] = {};
    for (int nt = 0; nt < 8; nt += 2) {
        float4v acc0 = {0.f, 0.f, 0.f, 0.f}, acc1 = {0.f, 0.f, 0.f, 0.f};
#pragma unroll
        for (int kt = 0; kt < 4; ++kt) {
            U8 b0, b1;
            b0.u = wf[(kt * 8 + nt) * 64 + lane];
            b1.u = wf[(kt * 8 + nt + 1) * 64 + lane];
            acc0 = __builtin_amdgcn_mfma_f32_16x16x32_bf16(a[kt].s, b0.s, acc0, 0, 0, 0);
            acc1 = __builtin_amdgcn_mfma_f32_16x16x32_bf16(a[kt].s, b1.s, acc1, 0, 0, 0);
        }
#pragma unroll
        for (int r = 0; r < 4; ++r) {
            const int row = crow0 + r;
            if (row < N) {
                Cb[(size_t)row * F + nt * 16 + ccol]       = (unsigned short)bf16rn(acc0[r]);
                Cb[(size_t)row * F + (nt + 1) * 16 + ccol] = (unsigned short)bf16rn(acc1[r]);
            }
        }
        if (asrc) {
            const float as0 = att_src[nt * 16 + ccol], as1 = att_src[(nt + 1) * 16 + ccol];
            const float ad0 = att_dst[nt * 16 + ccol], ad1 = att_dst[(nt + 1) * 16 + ccol];
#pragma unroll
            for (int r = 0; r < 4; ++r) {
                ps[r] += acc0[r] * as0 + acc1[r] * as1;
                pd[r] += acc0[r] * ad0 + acc1[r] * ad1;
            }
        }
    }
    if (asrc) {
#pragma unroll
        for (int r = 0; r < 4; ++r) {
            float s = ps[r], d = pd[r];
#pragma unroll
            for (int o = 8; o; o >>= 1) { s += __shfl_xor(s, o); d += __shfl_xor(d, o); }
            const int row = crow0 + r;
            if (ccol == 0 && row < N) { asrc[row] = s; adst[row] = d; }
        }
    }
}

// ---- CSR build via bucketed counting sort (bucket = dst>>8) ----
__global__ void bin_count(const int* __restrict__ ei, int* __restrict__ cmat) {
    __shared__ int lcnt[NBUCK];
    const int t = threadIdx.x, b = blockIdx.x;
    for (int i = t; i < NBUCK; i += 256) lcnt[i] = 0;
    __syncthreads();
    const int e0 = b * EPB;
#pragma unroll
    for (int i = 0; i < EPB / 256; ++i) {
        const int e = e0 + i * 256 + t;
        if (e < EP) {
            const int d = (e < NE) ? ei[NE + e] : e - NE;
            atomicAdd(&lcnt[d >> 8], 1);
        }
    }
    __syncthreads();
    for (int i = t; i < NBUCK; i += 256) cmat[i * NBE + b] = lcnt[i];
}

__global__ void scan_all(int* __restrict__ cmat) {
    __shared__ int part[1024];
    const int t = threadIdx.x;
    const int CH = (CMAT + 1023) / 1024;   // 40
    int loc[(CMAT + 1023) / 1024];
    const int lo = t * CH;
    int s = 0;
#pragma unroll
    for (int i = 0; i < CH; ++i) {
        const int j = lo + i;
        const int v = (j < CMAT) ? cmat[j] : 0;
        loc[i] = s; s += v;
    }
    part[t] = s;
    __syncthreads();
    for (int o = 1; o < 1024; o <<= 1) {
        const int u = (t >= o) ? part[t - o] : 0;
        __syncthreads();
        part[t] += u;
        __syncthreads();
    }
    const int base = part[t] - s;
#pragma unroll
    for (int i = 0; i < CH; ++i) {
        const int j = lo + i;
        if (j < CMAT) cmat[j] = base + loc[i];
    }
}

__global__ void bin_scatter(const int* __restrict__ ei, const int* __restrict__ cmat,
                            unsigned int* __restrict__ ebuf) {
    __shared__ int cur[NBUCK];
    const int t = threadIdx.x, b = blockIdx.x;
    for (int i = t; i < NBUCK; i += 256) cur[i] = cmat[i * NBE + b];
    __syncthreads();
    const int e0 = b * EPB;
#pragma unroll
    for (int i = 0; i < EPB / 256; ++i) {
        const int e = e0 + i * 256 + t;
        if (e < EP) {
            int s, d;
            if (e < NE) { s = ei[e]; d = ei[NE + e]; } else { s = d = e - NE; }
            const int p = atomicAdd(&cur[d >> 8], 1);
            ebuf[p] = (unsigned int)s | ((unsigned int)(d & 255) << 16);
        }
    }
}

__global__ void bucket_sort(const unsigned int* __restrict__ ebuf, const int* __restrict__ cmat,
                            int* __restrict__ row_start, unsigned short* __restrict__ csr16) {
    __shared__ unsigned int earr[BCAP];
    __shared__ unsigned short out16[BCAP];
    __shared__ int ecnt[256], epre[256];
    const int t = threadIdx.x, g = blockIdx.x;
    const int bstart = cmat[g * NBE];
    const int bend = (g == NBUCK - 1) ? EP : cmat[(g + 1) * NBE];
    const int m = bend - bstart;
    ecnt[t] = 0;
    __syncthreads();
    for (int i = t; i < m; i += 256) {
        const unsigned int v = ebuf[bstart + i];
        earr[i] = v;
        atomicAdd(&ecnt[v >> 16], 1);
    }
    __syncthreads();
    const int v0 = ecnt[t];
    epre[t] = v0;
    __syncthreads();
    for (int o = 1; o < 256; o <<= 1) {
        const int u = (t >= o) ? epre[t - o] : 0;
        __syncthreads();
        epre[t] += u;
        __syncthreads();
    }
    const int my_excl = epre[t] - v0;
    const int n = g * 256 + t;
    if (n <= NN) row_start[n] = bstart + my_excl;
    ecnt[t] = my_excl;
    __syncthreads();
    for (int i = t; i < m; i += 256) {
        const unsigned int v = earr[i];
        const int p = atomicAdd(&ecnt[v >> 16], 1);
        out16[p] = (unsigned short)(v & 0xffffu);
    }
    __syncthreads();
    for (int i = t; i < m; i += 256) csr16[bstart + i] = out16[i];
}

// ---- GAT gather: 2 waves per dst node (feature halves of 64); 8 lanes/edge,
// 8 edges per issue group, 2x unrolled -> 16 row-loads in flight per wave.
__global__ void gat_gather(const int* __restrict__ row_start, const unsigned short* __restrict__ csr_src,
                           const float* __restrict__ asrc, const float* __restrict__ adst,
                           const unsigned short* __restrict__ hb, const float* __restrict__ bias,
                           unsigned short* __restrict__ out) {
    const int wave = threadIdx.x >> 6;
    const int n = blockIdx.x * 2 + (wave >> 1);
    const int fh = wave & 1;
    const int lane = threadIdx.x & 63;
    if (n >= NN) return;
    const int oct = lane >> 3;                 // edge slot 0..7
    const int fo = fh * 64 + (lane & 7) * 8;   // this lane's 8-feature group
    const int lo = row_start[n], hi = row_start[n + 1];
    const float adn = adst[n];
    float den = 0.f;
    float accA[8] = {}, accB[8] = {};
    for (int base = lo; base < hi; base += 64) {
        const int cnt = min(64, hi - base);
        const int sv = (lane < cnt) ? (int)csr_src[base + lane] : 0;
        float ev = 0.f;
        if (lane < cnt) {
            float sc = asrc[sv] + adn;
            sc = sc > 0.f ? sc : 0.2f * sc;
            ev = __expf(sc);
        }
        den += ev;
        if (cnt == 64) {
#pragma unroll
            for (int j = 0; j < 64; j += 16) {
                const int   s0 = __shfl(sv, j + oct);
                const float w0 = __shfl(ev, j + oct);
                const int   s1 = __shfl(sv, j + 8 + oct);
                const float w1 = __shfl(ev, j + 8 + oct);
                const uint4 h0 = *(const uint4*)(hb + (size_t)s0 * F + fo);
                const uint4 h1 = *(const uint4*)(hb + (size_t)s1 * F + fo);
                bf8_fma(accA, w0, h0);
                bf8_fma(accB, w1, h1);
            }
        } else {
            for (int j = 0; j < cnt; j += 8) {   // jj <= 63; ev=0 pads beyond cnt
                const int   s0 = __shfl(sv, j + oct);
                const float w0 = __shfl(ev, j + oct);
                const uint4 h0 = *(const uint4*)(hb + (size_t)s0 * F + fo);
                bf8_fma(accA, w0, h0);
            }
        }
    }
    float acc[8];
#pragma unroll
    for (int i = 0; i < 8; ++i) {
        float v = accA[i] + accB[i];
        v += __shfl_xor(v, 8);
        v += __shfl_xor(v, 16);
        v += __shfl_xor(v, 32);
        acc[i] = v;
    }
    for (int o = 32; o; o >>= 1) den += __shfl_xor(den, o);
    const float inv = 1.f / den;               // den > 0 (self loop)
    if (lane < 8) {
        float v[8];
#pragma unroll
        for (int i = 0; i < 8; ++i) {
            v[i] = fmaf(acc[i], inv, bias[fo + i]);
            v[i] = v[i] > 0.f ? v[i] : 0.f;
        }
        uint4 pk;
        pk.x = pack2(v[0], v[1]); pk.y = pack2(v[2], v[3]);
        pk.z = pack2(v[4], v[5]); pk.w = pack2(v[6], v[7]);
        *(uint4*)(out + (size_t)n * F + fo) = pk;
    }
}

__global__ void make_dinv(const int* __restrict__ row_start, float* __restrict__ dinv) {
    const int n = blockIdx.x * blockDim.x + threadIdx.x;
    if (n >= NN) return;
    dinv[n] = rsqrtf((float)(row_start[n + 1] - row_start[n]));
}

// ---- GCN gather (same 2-wave/node structure) + fused mean-pool/head partials.
__global__ void gcn_gather_pool(const int* __restrict__ row_start, const unsigned short* __restrict__ csr_src,
                                const float* __restrict__ dinv, const unsigned short* __restrict__ hb,
                                const float* __restrict__ bias, const int* __restrict__ batch,
                                const float* __restrict__ Wf, float* __restrict__ gscr) {
    __shared__ int   sg[4];
    __shared__ float sp0[4], sp1[4];
    const int wave = threadIdx.x >> 6;
    const int n = blockIdx.x * 2 + (wave >> 1);
    const int fh = wave & 1;
    const int lane = threadIdx.x & 63;
    const int oct = lane >> 3;
    const int fo = fh * 64 + (lane & 7) * 8;
    if (threadIdx.x < 4) sg[threadIdx.x] = -1;
    float p0 = 0.f, p1 = 0.f;
    if (n < NN) {
        const int lo = row_start[n], hi = row_start[n + 1];
        const float dn = dinv[n];
        float accA[8] = {}, accB[8] = {};
        for (int base = lo; base < hi; base += 64) {
            const int cnt = min(64, hi - base);
            const int sv = (lane < cnt) ? (int)csr_src[base + lane] : 0;
            const float wv = (lane < cnt) ? dinv[sv] : 0.f;
            if (cnt == 64) {
#pragma unroll
                for (int j = 0; j < 64; j += 16) {
                    const int   s0 = __shfl(sv, j + oct);
                    const float w0 = __shfl(wv, j + oct);
                    const int   s1 = __shfl(sv, j + 8 + oct);
                    const float w1 = __shfl(wv, j + 8 + oct);
                    const uint4 h0 = *(const uint4*)(hb + (size_t)s0 * F + fo);
                    const uint4 h1 = *(const uint4*)(hb + (size_t)s1 * F + fo);
                    bf8_fma(accA, w0, h0);
                    bf8_fma(accB, w1, h1);
                }
            } else {
                for (int j = 0; j < cnt; j += 8) {
                    const int   s0 = __shfl(sv, j + oct);
                    const float w0 = __shfl(wv, j + oct);
                    const uint4 h0 = *(const uint4*)(hb + (size_t)s0 * F + fo);
                    bf8_fma(accA, w0, h0);
                }
            }
        }
        const float dnn = dn;
        float v[8];
#pragma unroll
        for (int i = 0; i < 8; ++i) {
            float a = accA[i] + accB[i];
            a += __shfl_xor(a, 8);
            a += __shfl_xor(a, 16);
            a += __shfl_xor(a, 32);
            v[i] = fmaf(a, dnn, bias[fo + i]);
            v[i] = v[i] > 0.f ? v[i] : 0.f;
        }
        // project to 2 classes: Wf rows fo..fo+7, layout [row][2] interleaved
        const float4 w0 = *(const float4*)(Wf + fo * 2);
        const float4 w1 = *(const float4*)(Wf + fo * 2 + 4);
        const float4 w2 = *(const float4*)(Wf + fo * 2 + 8);
        const float4 w3 = *(const float4*)(Wf + fo * 2 + 12);
        p0 = v[0]*w0.x + v[1]*w0.z + v[2]*w1.x + v[3]*w1.z +
             v[4]*w2.x + v[5]*w2.z + v[6]*w3.x + v[7]*w3.z;
        p1 = v[0]*w0.y + v[1]*w0.w + v[2]*w1.y + v[3]*w1.w +
             v[4]*w2.y + v[5]*w2.w + v[6]*w3.y + v[7]*w3.w;
        // all lanes hold per-feature-class totals; sum the 8 classes (lanes 0-7)
        for (int o = 4; o; o >>= 1) { p0 += __shfl_xor(p0, o); p1 += __shfl_xor(p1, o); }
    }
    if (lane == 0 && n < NN) { sg[wave] = batch[n]; sp0[wave] = p0; sp1[wave] = p1; }
    __syncthreads();
    if (threadIdx.x == 0) {
#pragma unroll
        for (int w = 0; w < 4; ++w) {
            const int g = sg[w];
            if (g < 0) continue;
            float q0 = sp0[w], q1 = sp1[w];
            for (int u = w + 1; u < 4; ++u) {
                if (sg[u] == g) { q0 += sp0[u]; q1 += sp1[u]; sg[u] = -1; }
            }
            atomicAdd(gscr + g * 32,     q0);
            atomicAdd(gscr + g * 32 + 1, q1);
        }
    }
}

__global__ void finalize(const float* __restrict__ gscr, const int* __restrict__ batch,
                         const float* __restrict__ bf, float* __restrict__ out) {
    const int g = threadIdx.x;   // 128
    int lo = 0, hi = NN;
    while (lo < hi) { int m = (lo + hi) >> 1; if (batch[m] < g) lo = m + 1; else hi = m; }
    int lo2 = lo, hi2 = NN;
    while (lo2 < hi2) { int m = (lo2 + hi2) >> 1; if (batch[m] < g + 1) lo2 = m + 1; else hi2 = m; }
    const float inv = 1.f / fmaxf((float)(lo2 - lo), 1.f);
    out[g * 2]     = gscr[g * 32]     * inv + bf[0];
    out[g * 2 + 1] = gscr[g * 32 + 1] * inv + bf[1];
}

extern "C" void kernel_launch(void* const* d_in, const int* in_sizes, int n_in,
                              void* d_out, int out_size, void* d_ws, size_t ws_size,
                              hipStream_t stream) {
    const float* x       = (const float*)d_in[0];
    const float* W1      = (const float*)d_in[1];
    const float* att_src = (const float*)d_in[2];
    const float* att_dst = (const float*)d_in[3];
    const float* b1      = (const float*)d_in[4];
    const float* W2      = (const float*)d_in[5];
    const float* b2      = (const float*)d_in[6];
    const float* Wf      = (const float*)d_in[7];
    const float* bf      = (const float*)d_in[8];
    const int*   ei      = (const int*)d_in[9];
    const int*   batch   = (const int*)d_in[10];
    float* out = (float*)d_out;

    unsigned short* xb   = (unsigned short*)d_ws;                   // [NN*F] bf16 x
    unsigned short* h1b  = xb + (size_t)NN * F;                     // [NN*F] bf16 gemm1 out
    unsigned short* hgb  = h1b + (size_t)NN * F;                    // [NN*F] bf16 GAT out
    unsigned short* h2b  = hgb + (size_t)NN * F;                    // [NN*F] bf16 gemm2 out
    float* asrc      = (float*)(h2b + (size_t)NN * F);              // [NN]
    float* adst      = asrc + NN;                                   // [NN]
    float* dinv      = adst + NN;                                   // [NN]
    float* gscr      = dinv + NN;                                   // [NG*32]
    int*   row_start = (int*)(gscr + NG * 32);                      // [NN+1]
    unsigned short* csr16 = (unsigned short*)(row_start + NN + 1);  // [EP]
    unsigned int*   ebuf  = (unsigned int*)(csr16 + EP);            // [EP]
    int*   cmat      = (int*)(ebuf + EP);                           // [CMAT]
    uint4* wf1       = (uint4*)(cmat + CMAT);                       // [2048] W1 frags
    uint4* wf2       = wf1 + 2048;                                  // [2048] W2 frags

    // one-shot weight packing + CSR build + input conversion
    pack_wfrag<<<8, 256, 0, stream>>>(W1, wf1);
    pack_wfrag<<<8, 256, 0, stream>>>(W2, wf2);
    bin_count<<<NBE, 256, 0, stream>>>(ei, cmat);
    cvt_bf16<<<(NN * F / 8 + 255) / 256, 256, 0, stream>>>(x, xb, NN * F / 8);
    scan_all<<<1, 1024, 0, stream>>>(cmat);
    bin_scatter<<<NBE, 256, 0, stream>>>(ei, cmat, ebuf);
    bucket_sort<<<NBUCK, 256, 0, stream>>>(ebuf, cmat, row_start, csr16);
    hipMemsetAsync(gscr, 0, NG * 32 * sizeof(float), stream);

    mfma_gemm<<<(NN + 63) / 64, 256, 0, stream>>>(xb, wf1, h1b, NN,
                                                  att_src, att_dst, asrc, adst);
    gat_gather<<<(NN + 1) / 2, 256, 0, stream>>>(row_start, csr16, asrc, adst, h1b, b1, hgb);
    mfma_gemm<<<(NN + 63) / 64, 256, 0, stream>>>(hgb, wf2, h2b, NN,
                                                  nullptr, nullptr, nullptr, nullptr);
    make_dinv<<<(NN + 255) / 256, 256, 0, stream>>>(row_start, dinv);
    gcn_gather_pool<<<(NN + 1) / 2, 256, 0, stream>>>(row_start, csr16, dinv, h2b, b2,
                                                      batch, Wf, gscr);
    finalize<<<1, NG, 0, stream>>>(gscr, batch, bf, out);
}

// Round 13
// 278.857 us; speedup vs baseline: 1.3780x; 1.3780x over previous
//
#include <hip/hip_runtime.h>

#define NN 50000
#define NE 800000
#define EP (NE + NN)      // edges + self loops = 850000
#define NG 128
#define F 128
#define NBE 208           // edge-pass blocks
#define EPB 4096          // edges per block (208*4096 >= EP)
#define NBUCK 196         // dst buckets of 256 nodes
#define CMAT (NBUCK * NBE)
#define BCAP 6144         // per-bucket edge cap (mean 4352)

typedef __attribute__((ext_vector_type(8))) short short8;
typedef __attribute__((ext_vector_type(4))) float float4v;
union U8 { uint4 u; short8 s; };

__device__ inline unsigned int bf16rn(float x) {   // RNE round to bf16 (low 16 bits)
    unsigned int u = __float_as_uint(x);
    u += 0x7fffu + ((u >> 16) & 1u);
    return u >> 16;
}
__device__ inline unsigned int pack2(float a, float b) {
    return bf16rn(a) | (bf16rn(b) << 16);
}
// 8 bf16 (uint4) -> 8 fma's into acc[0..7]
__device__ inline void bf8_fma(float* acc, float w, uint4 hv) {
    acc[0] = fmaf(w, __uint_as_float(hv.x << 16), acc[0]);
    acc[1] = fmaf(w, __uint_as_float(hv.x & 0xffff0000u), acc[1]);
    acc[2] = fmaf(w, __uint_as_float(hv.y << 16), acc[2]);
    acc[3] = fmaf(w, __uint_as_float(hv.y & 0xffff0000u), acc[3]);
    acc[4] = fmaf(w, __uint_as_float(hv.z << 16), acc[4]);
    acc[5] = fmaf(w, __uint_as_float(hv.z & 0xffff0000u), acc[5]);
    acc[6] = fmaf(w, __uint_as_float(hv.w << 16), acc[6]);
    acc[7] = fmaf(w, __uint_as_float(hv.w & 0xffff0000u), acc[7]);
}

// fp32 -> bf16 convert, 8 elements/thread
__global__ void cvt_bf16(const float* __restrict__ src, unsigned short* __restrict__ dst,
                         int n8) {
    const int i = blockIdx.x * blockDim.x + threadIdx.x;
    if (i >= n8) return;
    const float4 f0 = *(const float4*)(src + (size_t)i * 8);
    const float4 f1 = *(const float4*)(src + (size_t)i * 8 + 4);
    uint4 pk;
    pk.x = pack2(f0.x, f0.y); pk.y = pack2(f0.z, f0.w);
    pk.z = pack2(f1.x, f1.y); pk.w = pack2(f1.z, f1.w);
    *(uint4*)(dst + (size_t)i * 8) = pk;
}

// One-shot: pack W fp32 [128][128] into MFMA B-fragments (bf16), global image.
// frag f = kt*8+nt, lane l: B[k=kt*32+(l>>4)*8+j][n=nt*16+(l&15)], j=0..7 paired.
__global__ void pack_wfrag(const float* __restrict__ W, uint4* __restrict__ wf) {
    const int p = blockIdx.x * blockDim.x + threadIdx.x;   // 0..2047
    if (p >= 2048) return;
    const int f = p >> 6, l = p & 63;
    const int kt = f >> 3, nt = f & 7;
    const int rb = kt * 32 + ((l >> 4) << 3);
    const int col = nt * 16 + (l & 15);
    const float* wp = W + (size_t)rb * F + col;
    uint4 pk;
    pk.x = pack2(wp[0],     wp[F]);
    pk.y = pack2(wp[2 * F], wp[3 * F]);
    pk.z = pack2(wp[4 * F], wp[5 * F]);
    pk.w = pack2(wp[6 * F], wp[7 * F]);
    wf[p] = pk;
}

// C[N,128] = A[N,128] @ W via v_mfma_f32_16x16x32_bf16. No LDS, no barriers:
// B-fragments pre-packed in global (32 KB, L2-broadcast). 4 waves = 64 rows/block.
__global__ __launch_bounds__(256) void mfma_gemm(
        const unsigned short* __restrict__ Ab, const uint4* __restrict__ wf,
        unsigned short* __restrict__ Cb, int N,
        const float* __restrict__ att_src, const float* __restrict__ att_dst,
        float* __restrict__ asrc, float* __restrict__ adst) {
    const int t = threadIdx.x;
    const int wave = t >> 6, lane = t & 63;
    const int m0 = blockIdx.x * 64 + wave * 16;
    const int arow = m0 + (lane & 15);
    const int kq = (lane >> 4) << 3;
    U8 a[4];
#pragma unroll
    for (int kt = 0; kt < 4; ++kt) {
        if (arow < N) a[kt].u = *(const uint4*)(Ab + (size_t)arow * F + kt * 32 + kq);
        else          a[kt].u = make_uint4(0, 0, 0, 0);
    }
    const int ccol = lane & 15;
    const int crow0 = m0 + ((lane >> 4) << 2);
    float ps[4] = {}, pd[4] = {};
    for (int nt = 0; nt < 8; nt += 2) {
        float4v acc0 = {0.f, 0.f, 0.f, 0.f}, acc1 = {0.f, 0.f, 0.f, 0.f};
#pragma unroll
        for (int kt = 0; kt < 4; ++kt) {
            U8 b0, b1;
            b0.u = wf[(kt * 8 + nt) * 64 + lane];
            b1.u = wf[(kt * 8 + nt + 1) * 64 + lane];
            acc0 = __builtin_amdgcn_mfma_f32_16x16x32_bf16(a[kt].s, b0.s, acc0, 0, 0, 0);
            acc1 = __builtin_amdgcn_mfma_f32_16x16x32_bf16(a[kt].s, b1.s, acc1, 0, 0, 0);
        }
#pragma unroll
        for (int r = 0; r < 4; ++r) {
            const int row = crow0 + r;
            if (row < N) {
                Cb[(size_t)row * F + nt * 16 + ccol]       = (unsigned short)bf16rn(acc0[r]);
                Cb[(size_t)row * F + (nt + 1) * 16 + ccol] = (unsigned short)bf16rn(acc1[r]);
            }
        }
        if (asrc) {
            const float as0 = att_src[nt * 16 + ccol], as1 = att_src[(nt + 1) * 16 + ccol];
            const float ad0 = att_dst[nt * 16 + ccol], ad1 = att_dst[(nt + 1) * 16 + ccol];
#pragma unroll
            for (int r = 0; r < 4; ++r) {
                ps[r] += acc0[r] * as0 + acc1[r] * as1;
                pd[r] += acc0[r] * ad0 + acc1[r] * ad1;
            }
        }
    }
    if (asrc) {
#pragma unroll
        for (int r = 0; r < 4; ++r) {
            float s = ps[r], d = pd[r];
#pragma unroll
            for (int o = 8; o; o >>= 1) { s += __shfl_xor(s, o); d += __shfl_xor(d, o); }
            const int row = crow0 + r;
            if (ccol == 0 && row < N) { asrc[row] = s; adst[row] = d; }
        }
    }
}

// ---- CSR build via bucketed counting sort (bucket = dst>>8) ----
__global__ void bin_count(const int* __restrict__ ei, int* __restrict__ cmat) {
    __shared__ int lcnt[NBUCK];
    const int t = threadIdx.x, b = blockIdx.x;
    for (int i = t; i < NBUCK; i += 256) lcnt[i] = 0;
    __syncthreads();
    const int e0 = b * EPB;
#pragma unroll
    for (int i = 0; i < EPB / 256; ++i) {
        const int e = e0 + i * 256 + t;
        if (e < EP) {
            const int d = (e < NE) ? ei[NE + e] : e - NE;
            atomicAdd(&lcnt[d >> 8], 1);
        }
    }
    __syncthreads();
    for (int i = t; i < NBUCK; i += 256) cmat[i * NBE + b] = lcnt[i];
}

__global__ void scan_all(int* __restrict__ cmat) {
    __shared__ int part[1024];
    const int t = threadIdx.x;
    const int CH = (CMAT + 1023) / 1024;   // 40
    int loc[(CMAT + 1023) / 1024];
    const int lo = t * CH;
    int s = 0;
#pragma unroll
    for (int i = 0; i < CH; ++i) {
        const int j = lo + i;
        const int v = (j < CMAT) ? cmat[j] : 0;
        loc[i] = s; s += v;
    }
    part[t] = s;
    __syncthreads();
    for (int o = 1; o < 1024; o <<= 1) {
        const int u = (t >= o) ? part[t - o] : 0;
        __syncthreads();
        part[t] += u;
        __syncthreads();
    }
    const int base = part[t] - s;
#pragma unroll
    for (int i = 0; i < CH; ++i) {
        const int j = lo + i;
        if (j < CMAT) cmat[j] = base + loc[i];
    }
}

__global__ void bin_scatter(const int* __restrict__ ei, const int* __restrict__ cmat,
                            unsigned int* __restrict__ ebuf) {
    __shared__ int cur[NBUCK];
    const int t = threadIdx.x, b = blockIdx.x;
    for (int i = t; i < NBUCK; i += 256) cur[i] = cmat[i * NBE + b];
    __syncthreads();
    const int e0 = b * EPB;
#pragma unroll
    for (int i = 0; i < EPB / 256; ++i) {
        const int e = e0 + i * 256 + t;
        if (e < EP) {
            int s, d;
            if (e < NE) { s = ei[e]; d = ei[NE + e]; } else { s = d = e - NE; }
            const int p = atomicAdd(&cur[d >> 8], 1);
            ebuf[p] = (unsigned int)s | ((unsigned int)(d & 255) << 16);
        }
    }
}

// per-bucket LDS counting sort; also emits dinv[n]=rsqrt(deg) (deg in-register)
__global__ void bucket_sort(const unsigned int* __restrict__ ebuf, const int* __restrict__ cmat,
                            int* __restrict__ row_start, unsigned short* __restrict__ csr16,
                            float* __restrict__ dinv) {
    __shared__ unsigned int earr[BCAP];
    __shared__ unsigned short out16[BCAP];
    __shared__ int ecnt[256], epre[256];
    const int t = threadIdx.x, g = blockIdx.x;
    const int bstart = cmat[g * NBE];
    const int bend = (g == NBUCK - 1) ? EP : cmat[(g + 1) * NBE];
    const int m = bend - bstart;
    ecnt[t] = 0;
    __syncthreads();
    for (int i = t; i < m; i += 256) {
        const unsigned int v = ebuf[bstart + i];
        earr[i] = v;
        atomicAdd(&ecnt[v >> 16], 1);
    }
    __syncthreads();
    const int v0 = ecnt[t];
    epre[t] = v0;
    __syncthreads();
    for (int o = 1; o < 256; o <<= 1) {
        const int u = (t >= o) ? epre[t - o] : 0;
        __syncthreads();
        epre[t] += u;
        __syncthreads();
    }
    const int my_excl = epre[t] - v0;
    const int n = g * 256 + t;
    if (n <= NN) row_start[n] = bstart + my_excl;
    if (n < NN) dinv[n] = rsqrtf((float)v0);   // deg >= 1 (self loop)
    ecnt[t] = my_excl;
    __syncthreads();
    for (int i = t; i < m; i += 256) {
        const unsigned int v = earr[i];
        const int p = atomicAdd(&ecnt[v >> 16], 1);
        out16[p] = (unsigned short)(v & 0xffffu);
    }
    __syncthreads();
    for (int i = t; i < m; i += 256) csr16[bstart + i] = out16[i];
}

// ---- GAT gather (R11 structure): one wave/node, 16 lanes/edge over 256B rows.
__global__ void gat_gather(const int* __restrict__ row_start, const unsigned short* __restrict__ csr_src,
                           const float* __restrict__ asrc, const float* __restrict__ adst,
                           const unsigned short* __restrict__ hb, const float* __restrict__ bias,
                           unsigned short* __restrict__ out) {
    const int n = blockIdx.x * 4 + (threadIdx.x >> 6);
    const int lane = threadIdx.x & 63;
    if (n >= NN) return;
    const int quarter = lane >> 4;
    const int qo = (lane & 15) << 3;
    const int lo = row_start[n], hi = row_start[n + 1];
    const float adn = adst[n];
    float den = 0.f;
    float accA[8] = {}, accB[8] = {};
    for (int base = lo; base < hi; base += 64) {
        const int cnt = min(64, hi - base);
        const int sv = (lane < cnt) ? (int)csr_src[base + lane] : 0;
        float ev = 0.f;
        if (lane < cnt) {
            float sc = asrc[sv] + adn;
            sc = sc > 0.f ? sc : 0.2f * sc;
            ev = __expf(sc);
        }
        den += ev;
        int j = 0;
        for (; j + 16 <= cnt; j += 16) {
#pragma unroll
            for (int t = 0; t < 4; ++t) {
                const int jj = j + 4 * t + quarter;
                const int   s = __shfl(sv, jj);
                const float w = __shfl(ev, jj);
                const uint4 hv = *(const uint4*)(hb + (size_t)s * F + qo);
                bf8_fma((t & 1) ? accB : accA, w, hv);
            }
        }
        for (; j < cnt; j += 4) {
            const int jj = j + quarter;
            const int   s = __shfl(sv, jj);
            const float w = __shfl(ev, jj);
            const uint4 hv = *(const uint4*)(hb + (size_t)s * F + qo);
            bf8_fma(accA, w, hv);
        }
    }
    float acc[8];
#pragma unroll
    for (int i = 0; i < 8; ++i) {
        float v = accA[i] + accB[i];
        v += __shfl_xor(v, 16);
        v += __shfl_xor(v, 32);
        acc[i] = v;
    }
    for (int o = 32; o; o >>= 1) den += __shfl_xor(den, o);
    const float inv = 1.f / den;
    if (lane < 16) {
        float v[8];
#pragma unroll
        for (int i = 0; i < 8; ++i) {
            v[i] = fmaf(acc[i], inv, bias[qo + i]);
            v[i] = v[i] > 0.f ? v[i] : 0.f;
        }
        uint4 pk;
        pk.x = pack2(v[0], v[1]); pk.y = pack2(v[2], v[3]);
        pk.z = pack2(v[4], v[5]); pk.w = pack2(v[6], v[7]);
        *(uint4*)(out + (size_t)n * F + qo) = pk;
    }
}

// ---- GCN gather (R11 structure) + fused mean-pool/head partials.
__global__ void gcn_gather_pool(const int* __restrict__ row_start, const unsigned short* __restrict__ csr_src,
                                const float* __restrict__ dinv, const unsigned short* __restrict__ hb,
                                const float* __restrict__ bias, const int* __restrict__ batch,
                                const float* __restrict__ Wf, float* __restrict__ gscr) {
    __shared__ int   sg[4];
    __shared__ float sp0[4], sp1[4];
    const int wave = threadIdx.x >> 6;
    const int n = blockIdx.x * 4 + wave;
    const int lane = threadIdx.x & 63;
    const int quarter = lane >> 4;
    const int qo = (lane & 15) << 3;
    if (threadIdx.x < 4) sg[threadIdx.x] = -1;
    float p0 = 0.f, p1 = 0.f;
    if (n < NN) {
        const int lo = row_start[n], hi = row_start[n + 1];
        const float dn = dinv[n];
        float accA[8] = {}, accB[8] = {};
        for (int base = lo; base < hi; base += 64) {
            const int cnt = min(64, hi - base);
            const int sv = (lane < cnt) ? (int)csr_src[base + lane] : 0;
            const float wv = (lane < cnt) ? dinv[sv] : 0.f;
            int j = 0;
            for (; j + 16 <= cnt; j += 16) {
#pragma unroll
                for (int t = 0; t < 4; ++t) {
                    const int jj = j + 4 * t + quarter;
                    const int   s = __shfl(sv, jj);
                    const float w = __shfl(wv, jj);
                    const uint4 hv = *(const uint4*)(hb + (size_t)s * F + qo);
                    bf8_fma((t & 1) ? accB : accA, w, hv);
                }
            }
            for (; j < cnt; j += 4) {
                const int jj = j + quarter;
                const int   s = __shfl(sv, jj);
                const float w = __shfl(wv, jj);
                const uint4 hv = *(const uint4*)(hb + (size_t)s * F + qo);
                bf8_fma(accA, w, hv);
            }
        }
        float v[8];
#pragma unroll
        for (int i = 0; i < 8; ++i) {
            float a = accA[i] + accB[i];
            a += __shfl_xor(a, 16);
            a += __shfl_xor(a, 32);
            v[i] = fmaf(a, dn, bias[qo + i]);
            v[i] = v[i] > 0.f ? v[i] : 0.f;
        }
        const float4 w0 = *(const float4*)(Wf + qo * 2);
        const float4 w1 = *(const float4*)(Wf + qo * 2 + 4);
        const float4 w2 = *(const float4*)(Wf + qo * 2 + 8);
        const float4 w3 = *(const float4*)(Wf + qo * 2 + 12);
        p0 = v[0]*w0.x + v[1]*w0.z + v[2]*w1.x + v[3]*w1.z +
             v[4]*w2.x + v[5]*w2.z + v[6]*w3.x + v[7]*w3.z;
        p1 = v[0]*w0.y + v[1]*w0.w + v[2]*w1.y + v[3]*w1.w +
             v[4]*w2.y + v[5]*w2.w + v[6]*w3.y + v[7]*w3.w;
        for (int o = 8; o; o >>= 1) { p0 += __shfl_xor(p0, o); p1 += __shfl_xor(p1, o); }
    }
    if (lane == 0 && n < NN) { sg[wave] = batch[n]; sp0[wave] = p0; sp1[wave] = p1; }
    __syncthreads();
    if (threadIdx.x == 0) {
#pragma unroll
        for (int w = 0; w < 4; ++w) {
            const int g = sg[w];
            if (g < 0) continue;
            float q0 = sp0[w], q1 = sp1[w];
            for (int u = w + 1; u < 4; ++u) {
                if (sg[u] == g) { q0 += sp0[u]; q1 += sp1[u]; sg[u] = -1; }
            }
            atomicAdd(gscr + g * 32,     q0);
            atomicAdd(gscr + g * 32 + 1, q1);
        }
    }
}

__global__ void finalize(const float* __restrict__ gscr, const int* __restrict__ batch,
                         const float* __restrict__ bf, float* __restrict__ out) {
    const int g = threadIdx.x;   // 128
    int lo = 0, hi = NN;
    while (lo < hi) { int m = (lo + hi) >> 1; if (batch[m] < g) lo = m + 1; else hi = m; }
    int lo2 = lo, hi2 = NN;
    while (lo2 < hi2) { int m = (lo2 + hi2) >> 1; if (batch[m] < g + 1) lo2 = m + 1; else hi2 = m; }
    const float inv = 1.f / fmaxf((float)(lo2 - lo), 1.f);
    out[g * 2]     = gscr[g * 32]     * inv + bf[0];
    out[g * 2 + 1] = gscr[g * 32 + 1] * inv + bf[1];
}

extern "C" void kernel_launch(void* const* d_in, const int* in_sizes, int n_in,
                              void* d_out, int out_size, void* d_ws, size_t ws_size,
                              hipStream_t stream) {
    const float* x       = (const float*)d_in[0];
    const float* W1      = (const float*)d_in[1];
    const float* att_src = (const float*)d_in[2];
    const float* att_dst = (const float*)d_in[3];
    const float* b1      = (const float*)d_in[4];
    const float* W2      = (const float*)d_in[5];
    const float* b2      = (const float*)d_in[6];
    const float* Wf      = (const float*)d_in[7];
    const float* bf      = (const float*)d_in[8];
    const int*   ei      = (const int*)d_in[9];
    const int*   batch   = (const int*)d_in[10];
    float* out = (float*)d_out;

    unsigned short* xb   = (unsigned short*)d_ws;                   // [NN*F] bf16 x
    unsigned short* h1b  = xb + (size_t)NN * F;                     // [NN*F] bf16 gemm1 out
    unsigned short* hgb  = h1b + (size_t)NN * F;                    // [NN*F] bf16 GAT out
    unsigned short* h2b  = hgb + (size_t)NN * F;                    // [NN*F] bf16 gemm2 out
    float* asrc      = (float*)(h2b + (size_t)NN * F);              // [NN]
    float* adst      = asrc + NN;                                   // [NN]
    float* dinv      = adst + NN;                                   // [NN]
    float* gscr      = dinv + NN;                                   // [NG*32]
    int*   row_start = (int*)(gscr + NG * 32);                      // [NN+1]
    unsigned short* csr16 = (unsigned short*)(row_start + NN + 1);  // [EP]
    unsigned int*   ebuf  = (unsigned int*)(csr16 + EP);            // [EP]
    int*   cmat      = (int*)(ebuf + EP);                           // [CMAT]
    uint4* wf1       = (uint4*)(cmat + CMAT);                       // [2048] W1 frags
    uint4* wf2       = wf1 + 2048;                                  // [2048] W2 frags

    // one-shot weight packing + CSR build + input conversion
    pack_wfrag<<<8, 256, 0, stream>>>(W1, wf1);
    pack_wfrag<<<8, 256, 0, stream>>>(W2, wf2);
    bin_count<<<NBE, 256, 0, stream>>>(ei, cmat);
    cvt_bf16<<<(NN * F / 8 + 255) / 256, 256, 0, stream>>>(x, xb, NN * F / 8);
    scan_all<<<1, 1024, 0, stream>>>(cmat);
    bin_scatter<<<NBE, 256, 0, stream>>>(ei, cmat, ebuf);
    bucket_sort<<<NBUCK, 256, 0, stream>>>(ebuf, cmat, row_start, csr16, dinv);
    hipMemsetAsync(gscr, 0, NG * 32 * sizeof(float), stream);

    mfma_gemm<<<(NN + 63) / 64, 256, 0, stream>>>(xb, wf1, h1b, NN,
                                                  att_src, att_dst, asrc, adst);
    gat_gather<<<(NN + 3) / 4, 256, 0, stream>>>(row_start, csr16, asrc, adst, h1b, b1, hgb);
    mfma_gemm<<<(NN + 63) / 64, 256, 0, stream>>>(hgb, wf2, h2b, NN,
                                                  nullptr, nullptr, nullptr, nullptr);
    gcn_gather_pool<<<(NN + 3) / 4, 256, 0, stream>>>(row_start, csr16, dinv, h2b, b2,
                                                      batch, Wf, gscr);
    finalize<<<1, NG, 0, stream>>>(gscr, batch, bf, out);
}

// Round 14
// 275.357 us; speedup vs baseline: 1.3955x; 1.0127x over previous
//
#include <hip/hip_runtime.h>

#define NN 50000
#define NE 800000
#define EP (NE + NN)      // edges + self loops = 850000
#define NG 128
#define F 128
#define NBE 208           // edge-pass blocks
#define EPB 4096          // edges per block (208*4096 >= EP)
#define NBUCK 196         // dst buckets of 256 nodes
#define CMAT (NBUCK * NBE)
#define BCAP 6144         // per-bucket edge cap (mean 4352)

typedef __attribute__((ext_vector_type(8))) short short8;
typedef __attribute__((ext_vector_type(4))) float float4v;
union U8 { uint4 u; short8 s; };

__device__ inline unsigned int bf16rn(float x) {   // RNE round to bf16 (low 16 bits)
    unsigned int u = __float_as_uint(x);
    u += 0x7fffu + ((u >> 16) & 1u);
    return u >> 16;
}
__device__ inline unsigned int pack2(float a, float b) {
    return bf16rn(a) | (bf16rn(b) << 16);
}
// 8 bf16 (uint4) -> 8 fma's into acc[0..7]
__device__ inline void bf8_fma(float* acc, float w, uint4 hv) {
    acc[0] = fmaf(w, __uint_as_float(hv.x << 16), acc[0]);
    acc[1] = fmaf(w, __uint_as_float(hv.x & 0xffff0000u), acc[1]);
    acc[2] = fmaf(w, __uint_as_float(hv.y << 16), acc[2]);
    acc[3] = fmaf(w, __uint_as_float(hv.y & 0xffff0000u), acc[3]);
    acc[4] = fmaf(w, __uint_as_float(hv.z << 16), acc[4]);
    acc[5] = fmaf(w, __uint_as_float(hv.z & 0xffff0000u), acc[5]);
    acc[6] = fmaf(w, __uint_as_float(hv.w << 16), acc[6]);
    acc[7] = fmaf(w, __uint_as_float(hv.w & 0xffff0000u), acc[7]);
}

// One-shot: pack W1 and W2 fp32 [128][128] into MFMA B-fragments (bf16).
// frag f = kt*8+nt, lane l: B[k=kt*32+(l>>4)*8+j][n=nt*16+(l&15)], j=0..7 paired.
__global__ void pack_wfrag2(const float* __restrict__ W1, const float* __restrict__ W2,
                            uint4* __restrict__ wf) {
    const int p = blockIdx.x * blockDim.x + threadIdx.x;   // 0..4095
    if (p >= 4096) return;
    const float* W = (p < 2048) ? W1 : W2;
    const int q = p & 2047;
    const int f = q >> 6, l = q & 63;
    const int kt = f >> 3, nt = f & 7;
    const int rb = kt * 32 + ((l >> 4) << 3);
    const int col = nt * 16 + (l & 15);
    const float* wp = W + (size_t)rb * F + col;
    uint4 pk;
    pk.x = pack2(wp[0],     wp[F]);
    pk.y = pack2(wp[2 * F], wp[3 * F]);
    pk.z = pack2(wp[4 * F], wp[5 * F]);
    pk.w = pack2(wp[6 * F], wp[7 * F]);
    wf[p] = pk;
}

// C[N,128] = A[N,128] @ W via v_mfma_f32_16x16x32_bf16. No LDS, no barriers:
// B-fragments pre-packed in global (32 KB, L2-broadcast). 4 waves = 64 rows/block.
// A read either as bf16 (Ab) or fp32 (Af, converted in-register; gemm1 path).
__global__ __launch_bounds__(256) void mfma_gemm(
        const unsigned short* __restrict__ Ab, const float* __restrict__ Af,
        const uint4* __restrict__ wf,
        unsigned short* __restrict__ Cb, int N,
        const float* __restrict__ att_src, const float* __restrict__ att_dst,
        float* __restrict__ asrc, float* __restrict__ adst) {
    const int t = threadIdx.x;
    const int wave = t >> 6, lane = t & 63;
    const int m0 = blockIdx.x * 64 + wave * 16;
    const int arow = m0 + (lane & 15);
    const int kq = (lane >> 4) << 3;
    U8 a[4];
#pragma unroll
    for (int kt = 0; kt < 4; ++kt) {
        if (arow < N) {
            if (Af) {
                const float* ap = Af + (size_t)arow * F + kt * 32 + kq;
                const float4 f0 = *(const float4*)ap;
                const float4 f1 = *(const float4*)(ap + 4);
                a[kt].u = make_uint4(pack2(f0.x, f0.y), pack2(f0.z, f0.w),
                                     pack2(f1.x, f1.y), pack2(f1.z, f1.w));
            } else {
                a[kt].u = *(const uint4*)(Ab + (size_t)arow * F + kt * 32 + kq);
            }
        } else {
            a[kt].u = make_uint4(0, 0, 0, 0);
        }
    }
    const int ccol = lane & 15;
    const int crow0 = m0 + ((lane >> 4) << 2);
    float ps[4] = {}, pd[4] = {};
    for (int nt = 0; nt < 8; nt += 2) {
        float4v acc0 = {0.f, 0.f, 0.f, 0.f}, acc1 = {0.f, 0.f, 0.f, 0.f};
#pragma unroll
        for (int kt = 0; kt < 4; ++kt) {
            U8 b0, b1;
            b0.u = wf[(kt * 8 + nt) * 64 + lane];
            b1.u = wf[(kt * 8 + nt + 1) * 64 + lane];
            acc0 = __builtin_amdgcn_mfma_f32_16x16x32_bf16(a[kt].s, b0.s, acc0, 0, 0, 0);
            acc1 = __builtin_amdgcn_mfma_f32_16x16x32_bf16(a[kt].s, b1.s, acc1, 0, 0, 0);
        }
#pragma unroll
        for (int r = 0; r < 4; ++r) {
            const int row = crow0 + r;
            if (row < N) {
                Cb[(size_t)row * F + nt * 16 + ccol]       = (unsigned short)bf16rn(acc0[r]);
                Cb[(size_t)row * F + (nt + 1) * 16 + ccol] = (unsigned short)bf16rn(acc1[r]);
            }
        }
        if (asrc) {
            const float as0 = att_src[nt * 16 + ccol], as1 = att_src[(nt + 1) * 16 + ccol];
            const float ad0 = att_dst[nt * 16 + ccol], ad1 = att_dst[(nt + 1) * 16 + ccol];
#pragma unroll
            for (int r = 0; r < 4; ++r) {
                ps[r] += acc0[r] * as0 + acc1[r] * as1;
                pd[r] += acc0[r] * ad0 + acc1[r] * ad1;
            }
        }
    }
    if (asrc) {
#pragma unroll
        for (int r = 0; r < 4; ++r) {
            float s = ps[r], d = pd[r];
#pragma unroll
            for (int o = 8; o; o >>= 1) { s += __shfl_xor(s, o); d += __shfl_xor(d, o); }
            const int row = crow0 + r;
            if (ccol == 0 && row < N) { asrc[row] = s; adst[row] = d; }
        }
    }
}

// ---- CSR build via bucketed counting sort (bucket = dst>>8) ----
__global__ void bin_count(const int* __restrict__ ei, int* __restrict__ cmat,
                          float* __restrict__ gscr) {
    __shared__ int lcnt[NBUCK];
    const int t = threadIdx.x, b = blockIdx.x;
    if (b == 0) {                       // fold gscr zeroing in (written much later)
        for (int i = t; i < NG * 32; i += 256) gscr[i] = 0.f;
    }
    for (int i = t; i < NBUCK; i += 256) lcnt[i] = 0;
    __syncthreads();
    const int e0 = b * EPB;
#pragma unroll
    for (int i = 0; i < EPB / 256; ++i) {
        const int e = e0 + i * 256 + t;
        if (e < EP) {
            const int d = (e < NE) ? ei[NE + e] : e - NE;
            atomicAdd(&lcnt[d >> 8], 1);
        }
    }
    __syncthreads();
    for (int i = t; i < NBUCK; i += 256) cmat[i * NBE + b] = lcnt[i];
}

__global__ void scan_all(int* __restrict__ cmat) {
    __shared__ int part[1024];
    const int t = threadIdx.x;
    const int CH = (CMAT + 1023) / 1024;   // 40
    int loc[(CMAT + 1023) / 1024];
    const int lo = t * CH;
    int s = 0;
#pragma unroll
    for (int i = 0; i < CH; ++i) {
        const int j = lo + i;
        const int v = (j < CMAT) ? cmat[j] : 0;
        loc[i] = s; s += v;
    }
    part[t] = s;
    __syncthreads();
    for (int o = 1; o < 1024; o <<= 1) {
        const int u = (t >= o) ? part[t - o] : 0;
        __syncthreads();
        part[t] += u;
        __syncthreads();
    }
    const int base = part[t] - s;
#pragma unroll
    for (int i = 0; i < CH; ++i) {
        const int j = lo + i;
        if (j < CMAT) cmat[j] = base + loc[i];
    }
}

__global__ void bin_scatter(const int* __restrict__ ei, const int* __restrict__ cmat,
                            unsigned int* __restrict__ ebuf) {
    __shared__ int cur[NBUCK];
    const int t = threadIdx.x, b = blockIdx.x;
    for (int i = t; i < NBUCK; i += 256) cur[i] = cmat[i * NBE + b];
    __syncthreads();
    const int e0 = b * EPB;
#pragma unroll
    for (int i = 0; i < EPB / 256; ++i) {
        const int e = e0 + i * 256 + t;
        if (e < EP) {
            int s, d;
            if (e < NE) { s = ei[e]; d = ei[NE + e]; } else { s = d = e - NE; }
            const int p = atomicAdd(&cur[d >> 8], 1);
            ebuf[p] = (unsigned int)s | ((unsigned int)(d & 255) << 16);
        }
    }
}

// per-bucket LDS counting sort; also emits dinv[n]=rsqrt(deg)
__global__ void bucket_sort(const unsigned int* __restrict__ ebuf, const int* __restrict__ cmat,
                            int* __restrict__ row_start, unsigned short* __restrict__ csr16,
                            float* __restrict__ dinv) {
    __shared__ unsigned int earr[BCAP];
    __shared__ unsigned short out16[BCAP];
    __shared__ int ecnt[256], epre[256];
    const int t = threadIdx.x, g = blockIdx.x;
    const int bstart = cmat[g * NBE];
    const int bend = (g == NBUCK - 1) ? EP : cmat[(g + 1) * NBE];
    const int m = bend - bstart;
    ecnt[t] = 0;
    __syncthreads();
    for (int i = t; i < m; i += 256) {
        const unsigned int v = ebuf[bstart + i];
        earr[i] = v;
        atomicAdd(&ecnt[v >> 16], 1);
    }
    __syncthreads();
    const int v0 = ecnt[t];
    epre[t] = v0;
    __syncthreads();
    for (int o = 1; o < 256; o <<= 1) {
        const int u = (t >= o) ? epre[t - o] : 0;
        __syncthreads();
        epre[t] += u;
        __syncthreads();
    }
    const int my_excl = epre[t] - v0;
    const int n = g * 256 + t;
    if (n <= NN) row_start[n] = bstart + my_excl;
    if (n < NN) dinv[n] = rsqrtf((float)v0);   // deg >= 1 (self loop)
    ecnt[t] = my_excl;
    __syncthreads();
    for (int i = t; i < m; i += 256) {
        const unsigned int v = earr[i];
        const int p = atomicAdd(&ecnt[v >> 16], 1);
        out16[p] = (unsigned short)(v & 0xffffu);
    }
    __syncthreads();
    for (int i = t; i < m; i += 256) csr16[bstart + i] = out16[i];
}

// ---- GAT gather: one wave/node, 16 lanes/edge over 256B rows.
// Explicit 8-deep load batching (pads to 32 edges with zero weights).
__global__ void gat_gather(const int* __restrict__ row_start, const unsigned short* __restrict__ csr_src,
                           const float* __restrict__ asrc, const float* __restrict__ adst,
                           const unsigned short* __restrict__ hb, const float* __restrict__ bias,
                           unsigned short* __restrict__ out) {
    const int n = blockIdx.x * 4 + (threadIdx.x >> 6);
    const int lane = threadIdx.x & 63;
    if (n >= NN) return;
    const int quarter = lane >> 4;
    const int qo = (lane & 15) << 3;
    const int lo = row_start[n], hi = row_start[n + 1];
    const float adn = adst[n];
    float den = 0.f;
    float accA[8] = {}, accB[8] = {};
    for (int base = lo; base < hi; base += 64) {
        const int cnt = min(64, hi - base);
        const int sv = (lane < cnt) ? (int)csr_src[base + lane] : 0;
        float ev = 0.f;
        if (lane < cnt) {
            float sc = asrc[sv] + adn;
            sc = sc > 0.f ? sc : 0.2f * sc;
            ev = __expf(sc);
        }
        den += ev;
        for (int j = 0; j < cnt; j += 32) {   // jj = j+4t+quarter <= 63 always
            int ss[8]; float ww[8]; uint4 hv[8];
#pragma unroll
            for (int t = 0; t < 8; ++t) {
                const int jj = j + 4 * t + quarter;
                ss[t] = __shfl(sv, jj);
                ww[t] = __shfl(ev, jj);       // 0 beyond cnt -> padded edges no-op
            }
#pragma unroll
            for (int t = 0; t < 8; ++t)
                hv[t] = *(const uint4*)(hb + (size_t)ss[t] * F + qo);
#pragma unroll
            for (int t = 0; t < 8; ++t)
                bf8_fma((t & 1) ? accB : accA, ww[t], hv[t]);
        }
    }
    float acc[8];
#pragma unroll
    for (int i = 0; i < 8; ++i) {
        float v = accA[i] + accB[i];
        v += __shfl_xor(v, 16);
        v += __shfl_xor(v, 32);
        acc[i] = v;
    }
    for (int o = 32; o; o >>= 1) den += __shfl_xor(den, o);
    const float inv = 1.f / den;              // den > 0 (self loop)
    if (lane < 16) {
        float v[8];
#pragma unroll
        for (int i = 0; i < 8; ++i) {
            v[i] = fmaf(acc[i], inv, bias[qo + i]);
            v[i] = v[i] > 0.f ? v[i] : 0.f;
        }
        uint4 pk;
        pk.x = pack2(v[0], v[1]); pk.y = pack2(v[2], v[3]);
        pk.z = pack2(v[4], v[5]); pk.w = pack2(v[6], v[7]);
        *(uint4*)(out + (size_t)n * F + qo) = pk;
    }
}

// ---- GCN gather (same batching) + fused mean-pool/head partials.
__global__ void gcn_gather_pool(const int* __restrict__ row_start, const unsigned short* __restrict__ csr_src,
                                const float* __restrict__ dinv, const unsigned short* __restrict__ hb,
                                const float* __restrict__ bias, const int* __restrict__ batch,
                                const float* __restrict__ Wf, float* __restrict__ gscr) {
    __shared__ int   sg[4];
    __shared__ float sp0[4], sp1[4];
    const int wave = threadIdx.x >> 6;
    const int n = blockIdx.x * 4 + wave;
    const int lane = threadIdx.x & 63;
    const int quarter = lane >> 4;
    const int qo = (lane & 15) << 3;
    if (threadIdx.x < 4) sg[threadIdx.x] = -1;
    float p0 = 0.f, p1 = 0.f;
    if (n < NN) {
        const int lo = row_start[n], hi = row_start[n + 1];
        const float dn = dinv[n];
        float accA[8] = {}, accB[8] = {};
        for (int base = lo; base < hi; base += 64) {
            const int cnt = min(64, hi - base);
            const int sv = (lane < cnt) ? (int)csr_src[base + lane] : 0;
            const float wv = (lane < cnt) ? dinv[sv] : 0.f;
            for (int j = 0; j < cnt; j += 32) {
                int ss[8]; float ww[8]; uint4 hv[8];
#pragma unroll
                for (int t = 0; t < 8; ++t) {
                    const int jj = j + 4 * t + quarter;
                    ss[t] = __shfl(sv, jj);
                    ww[t] = __shfl(wv, jj);
                }
#pragma unroll
                for (int t = 0; t < 8; ++t)
                    hv[t] = *(const uint4*)(hb + (size_t)ss[t] * F + qo);
#pragma unroll
                for (int t = 0; t < 8; ++t)
                    bf8_fma((t & 1) ? accB : accA, ww[t], hv[t]);
            }
        }
        float v[8];
#pragma unroll
        for (int i = 0; i < 8; ++i) {
            float a = accA[i] + accB[i];
            a += __shfl_xor(a, 16);
            a += __shfl_xor(a, 32);
            v[i] = fmaf(a, dn, bias[qo + i]);
            v[i] = v[i] > 0.f ? v[i] : 0.f;
        }
        const float4 w0 = *(const float4*)(Wf + qo * 2);
        const float4 w1 = *(const float4*)(Wf + qo * 2 + 4);
        const float4 w2 = *(const float4*)(Wf + qo * 2 + 8);
        const float4 w3 = *(const float4*)(Wf + qo * 2 + 12);
        p0 = v[0]*w0.x + v[1]*w0.z + v[2]*w1.x + v[3]*w1.z +
             v[4]*w2.x + v[5]*w2.z + v[6]*w3.x + v[7]*w3.z;
        p1 = v[0]*w0.y + v[1]*w0.w + v[2]*w1.y + v[3]*w1.w +
             v[4]*w2.y + v[5]*w2.w + v[6]*w3.y + v[7]*w3.w;
        for (int o = 8; o; o >>= 1) { p0 += __shfl_xor(p0, o); p1 += __shfl_xor(p1, o); }
    }
    if (lane == 0 && n < NN) { sg[wave] = batch[n]; sp0[wave] = p0; sp1[wave] = p1; }
    __syncthreads();
    if (threadIdx.x == 0) {
#pragma unroll
        for (int w = 0; w < 4; ++w) {
            const int g = sg[w];
            if (g < 0) continue;
            float q0 = sp0[w], q1 = sp1[w];
            for (int u = w + 1; u < 4; ++u) {
                if (sg[u] == g) { q0 += sp0[u]; q1 += sp1[u]; sg[u] = -1; }
            }
            atomicAdd(gscr + g * 32,     q0);
            atomicAdd(gscr + g * 32 + 1, q1);
        }
    }
}

__global__ void finalize(const float* __restrict__ gscr, const int* __restrict__ batch,
                         const float* __restrict__ bf, float* __restrict__ out) {
    const int g = threadIdx.x;   // 128
    int lo = 0, hi = NN;
    while (lo < hi) { int m = (lo + hi) >> 1; if (batch[m] < g) lo = m + 1; else hi = m; }
    int lo2 = lo, hi2 = NN;
    while (lo2 < hi2) { int m = (lo2 + hi2) >> 1; if (batch[m] < g + 1) lo2 = m + 1; else hi2 = m; }
    const float inv = 1.f / fmaxf((float)(lo2 - lo), 1.f);
    out[g * 2]     = gscr[g * 32]     * inv + bf[0];
    out[g * 2 + 1] = gscr[g * 32 + 1] * inv + bf[1];
}

extern "C" void kernel_launch(void* const* d_in, const int* in_sizes, int n_in,
                              void* d_out, int out_size, void* d_ws, size_t ws_size,
                              hipStream_t stream) {
    const float* x       = (const float*)d_in[0];
    const float* W1      = (const float*)d_in[1];
    const float* att_src = (const float*)d_in[2];
    const float* att_dst = (const float*)d_in[3];
    const float* b1      = (const float*)d_in[4];
    const float* W2      = (const float*)d_in[5];
    const float* b2      = (const float*)d_in[6];
    const float* Wf      = (const float*)d_in[7];
    const float* bf      = (const float*)d_in[8];
    const int*   ei      = (const int*)d_in[9];
    const int*   batch   = (const int*)d_in[10];
    float* out = (float*)d_out;

    unsigned short* h1b  = (unsigned short*)d_ws;                   // [NN*F] bf16 gemm1 out
    unsigned short* hgb  = h1b + (size_t)NN * F;                    // [NN*F] bf16 GAT out
    unsigned short* h2b  = hgb + (size_t)NN * F;                    // [NN*F] bf16 gemm2 out
    float* asrc      = (float*)(h2b + (size_t)NN * F);              // [NN]
    float* adst      = asrc + NN;                                   // [NN]
    float* dinv      = adst + NN;                                   // [NN]
    float* gscr      = dinv + NN;                                   // [NG*32]
    int*   row_start = (int*)(gscr + NG * 32);                      // [NN+1]
    unsigned short* csr16 = (unsigned short*)(row_start + NN + 1);  // [EP]
    unsigned int*   ebuf  = (unsigned int*)(csr16 + EP);            // [EP]
    int*   cmat      = (int*)(ebuf + EP);                           // [CMAT]
    uint4* wf1       = (uint4*)(cmat + CMAT);                       // [2048] W1 frags
    uint4* wf2       = wf1 + 2048;                                  // [2048] W2 frags

    // one-shot weight packing + CSR build (gscr zeroed inside bin_count)
    pack_wfrag2<<<16, 256, 0, stream>>>(W1, W2, wf1);
    bin_count<<<NBE, 256, 0, stream>>>(ei, cmat, gscr);
    scan_all<<<1, 1024, 0, stream>>>(cmat);
    bin_scatter<<<NBE, 256, 0, stream>>>(ei, cmat, ebuf);
    bucket_sort<<<NBUCK, 256, 0, stream>>>(ebuf, cmat, row_start, csr16, dinv);

    mfma_gemm<<<(NN + 63) / 64, 256, 0, stream>>>(nullptr, x, wf1, h1b, NN,
                                                  att_src, att_dst, asrc, adst);
    gat_gather<<<(NN + 3) / 4, 256, 0, stream>>>(row_start, csr16, asrc, adst, h1b, b1, hgb);
    mfma_gemm<<<(NN + 63) / 64, 256, 0, stream>>>(hgb, nullptr, wf2, h2b, NN,
                                                  nullptr, nullptr, nullptr, nullptr);
    gcn_gather_pool<<<(NN + 3) / 4, 256, 0, stream>>>(row_start, csr16, dinv, h2b, b2,
                                                      batch, Wf, gscr);
    finalize<<<1, NG, 0, stream>>>(gscr, batch, bf, out);
}

// Round 15
// 269.972 us; speedup vs baseline: 1.4233x; 1.0199x over previous
//
#include <hip/hip_runtime.h>

#define NN 50000
#define NE 800000
#define EP (NE + NN)      // edges + self loops = 850000
#define NG 128
#define F 128
#define NBE 208           // edge-pass blocks
#define EPB 4096          // edges per block (208*4096 >= EP)
#define NBUCK 196         // dst buckets of 256 nodes
#define CMAT (NBUCK * NBE)
#define BCAP 6144         // per-bucket edge cap (mean 4352)

typedef __attribute__((ext_vector_type(8))) short short8;
typedef __attribute__((ext_vector_type(4))) float float4v;
union U8 { uint4 u; short8 s; };

__device__ inline unsigned int bf16rn(float x) {   // RNE round to bf16 (low 16 bits)
    unsigned int u = __float_as_uint(x);
    u += 0x7fffu + ((u >> 16) & 1u);
    return u >> 16;
}
__device__ inline unsigned int pack2(float a, float b) {
    return bf16rn(a) | (bf16rn(b) << 16);
}
// 8 bf16 (uint4) -> 8 fma's into acc[0..7]
__device__ inline void bf8_fma(float* acc, float w, uint4 hv) {
    acc[0] = fmaf(w, __uint_as_float(hv.x << 16), acc[0]);
    acc[1] = fmaf(w, __uint_as_float(hv.x & 0xffff0000u), acc[1]);
    acc[2] = fmaf(w, __uint_as_float(hv.y << 16), acc[2]);
    acc[3] = fmaf(w, __uint_as_float(hv.y & 0xffff0000u), acc[3]);
    acc[4] = fmaf(w, __uint_as_float(hv.z << 16), acc[4]);
    acc[5] = fmaf(w, __uint_as_float(hv.z & 0xffff0000u), acc[5]);
    acc[6] = fmaf(w, __uint_as_float(hv.w << 16), acc[6]);
    acc[7] = fmaf(w, __uint_as_float(hv.w & 0xffff0000u), acc[7]);
}

// One-shot: pack W1 and W2 fp32 [128][128] into MFMA B-fragments (bf16).
// frag f = kt*8+nt, lane l: B[k=kt*32+(l>>4)*8+j][n=nt*16+(l&15)], j=0..7 paired.
__global__ void pack_wfrag2(const float* __restrict__ W1, const float* __restrict__ W2,
                            uint4* __restrict__ wf) {
    const int p = blockIdx.x * blockDim.x + threadIdx.x;   // 0..4095
    if (p >= 4096) return;
    const float* W = (p < 2048) ? W1 : W2;
    const int q = p & 2047;
    const int f = q >> 6, l = q & 63;
    const int kt = f >> 3, nt = f & 7;
    const int rb = kt * 32 + ((l >> 4) << 3);
    const int col = nt * 16 + (l & 15);
    const float* wp = W + (size_t)rb * F + col;
    uint4 pk;
    pk.x = pack2(wp[0],     wp[F]);
    pk.y = pack2(wp[2 * F], wp[3 * F]);
    pk.z = pack2(wp[4 * F], wp[5 * F]);
    pk.w = pack2(wp[6 * F], wp[7 * F]);
    wf[p] = pk;
}

// C[N,128] = A[N,128] @ W via v_mfma_f32_16x16x32_bf16. No LDS, no barriers:
// B-fragments pre-packed in global (32 KB, L2-broadcast). 4 waves = 64 rows/block.
// A read either as bf16 (Ab) or fp32 (Af, converted in-register; gemm1 path).
__global__ __launch_bounds__(256) void mfma_gemm(
        const unsigned short* __restrict__ Ab, const float* __restrict__ Af,
        const uint4* __restrict__ wf,
        unsigned short* __restrict__ Cb, int N,
        const float* __restrict__ att_src, const float* __restrict__ att_dst,
        float* __restrict__ asrc, float* __restrict__ adst) {
    const int t = threadIdx.x;
    const int wave = t >> 6, lane = t & 63;
    const int m0 = blockIdx.x * 64 + wave * 16;
    const int arow = m0 + (lane & 15);
    const int kq = (lane >> 4) << 3;
    U8 a[4];
#pragma unroll
    for (int kt = 0; kt < 4; ++kt) {
        if (arow < N) {
            if (Af) {
                const float* ap = Af + (size_t)arow * F + kt * 32 + kq;
                const float4 f0 = *(const float4*)ap;
                const float4 f1 = *(const float4*)(ap + 4);
                a[kt].u = make_uint4(pack2(f0.x, f0.y), pack2(f0.z, f0.w),
                                     pack2(f1.x, f1.y), pack2(f1.z, f1.w));
            } else {
                a[kt].u = *(const uint4*)(Ab + (size_t)arow * F + kt * 32 + kq);
            }
        } else {
            a[kt].u = make_uint4(0, 0, 0, 0);
        }
    }
    const int ccol = lane & 15;
    const int crow0 = m0 + ((lane >> 4) << 2);
    float ps[4] = {}, pd[4] = {};
    for (int nt = 0; nt < 8; nt += 2) {
        float4v acc0 = {0.f, 0.f, 0.f, 0.f}, acc1 = {0.f, 0.f, 0.f, 0.f};
#pragma unroll
        for (int kt = 0; kt < 4; ++kt) {
            U8 b0, b1;
            b0.u = wf[(kt * 8 + nt) * 64 + lane];
            b1.u = wf[(kt * 8 + nt + 1) * 64 + lane];
            acc0 = __builtin_amdgcn_mfma_f32_16x16x32_bf16(a[kt].s, b0.s, acc0, 0, 0, 0);
            acc1 = __builtin_amdgcn_mfma_f32_16x16x32_bf16(a[kt].s, b1.s, acc1, 0, 0, 0);
        }
#pragma unroll
        for (int r = 0; r < 4; ++r) {
            const int row = crow0 + r;
            if (row < N) {
                Cb[(size_t)row * F + nt * 16 + ccol]       = (unsigned short)bf16rn(acc0[r]);
                Cb[(size_t)row * F + (nt + 1) * 16 + ccol] = (unsigned short)bf16rn(acc1[r]);
            }
        }
        if (asrc) {
            const float as0 = att_src[nt * 16 + ccol], as1 = att_src[(nt + 1) * 16 + ccol];
            const float ad0 = att_dst[nt * 16 + ccol], ad1 = att_dst[(nt + 1) * 16 + ccol];
#pragma unroll
            for (int r = 0; r < 4; ++r) {
                ps[r] += acc0[r] * as0 + acc1[r] * as1;
                pd[r] += acc0[r] * ad0 + acc1[r] * ad1;
            }
        }
    }
    if (asrc) {
#pragma unroll
        for (int r = 0; r < 4; ++r) {
            float s = ps[r], d = pd[r];
#pragma unroll
            for (int o = 8; o; o >>= 1) { s += __shfl_xor(s, o); d += __shfl_xor(d, o); }
            const int row = crow0 + r;
            if (ccol == 0 && row < N) { asrc[row] = s; adst[row] = d; }
        }
    }
}

// ---- CSR build via bucketed counting sort (bucket = dst>>8) ----
__global__ void bin_count(const int* __restrict__ ei, int* __restrict__ cmat,
                          float* __restrict__ gscr) {
    __shared__ int lcnt[NBUCK];
    const int t = threadIdx.x, b = blockIdx.x;
    if (b == 0) {                       // fold gscr zeroing in (written much later)
        for (int i = t; i < NG * 32; i += 256) gscr[i] = 0.f;
    }
    for (int i = t; i < NBUCK; i += 256) lcnt[i] = 0;
    __syncthreads();
    const int e0 = b * EPB;
#pragma unroll
    for (int i = 0; i < EPB / 256; ++i) {
        const int e = e0 + i * 256 + t;
        if (e < EP) {
            const int d = (e < NE) ? ei[NE + e] : e - NE;
            atomicAdd(&lcnt[d >> 8], 1);
        }
    }
    __syncthreads();
    for (int i = t; i < NBUCK; i += 256) cmat[i * NBE + b] = lcnt[i];
}

__global__ void scan_all(int* __restrict__ cmat) {
    __shared__ int part[1024];
    const int t = threadIdx.x;
    const int CH = (CMAT + 1023) / 1024;   // 40
    int loc[(CMAT + 1023) / 1024];
    const int lo = t * CH;
    int s = 0;
#pragma unroll
    for (int i = 0; i < CH; ++i) {
        const int j = lo + i;
        const int v = (j < CMAT) ? cmat[j] : 0;
        loc[i] = s; s += v;
    }
    part[t] = s;
    __syncthreads();
    for (int o = 1; o < 1024; o <<= 1) {
        const int u = (t >= o) ? part[t - o] : 0;
        __syncthreads();
        part[t] += u;
        __syncthreads();
    }
    const int base = part[t] - s;
#pragma unroll
    for (int i = 0; i < CH; ++i) {
        const int j = lo + i;
        if (j < CMAT) cmat[j] = base + loc[i];
    }
}

__global__ void bin_scatter(const int* __restrict__ ei, const int* __restrict__ cmat,
                            unsigned int* __restrict__ ebuf) {
    __shared__ int cur[NBUCK];
    const int t = threadIdx.x, b = blockIdx.x;
    for (int i = t; i < NBUCK; i += 256) cur[i] = cmat[i * NBE + b];
    __syncthreads();
    const int e0 = b * EPB;
#pragma unroll
    for (int i = 0; i < EPB / 256; ++i) {
        const int e = e0 + i * 256 + t;
        if (e < EP) {
            int s, d;
            if (e < NE) { s = ei[e]; d = ei[NE + e]; } else { s = d = e - NE; }
            const int p = atomicAdd(&cur[d >> 8], 1);
            ebuf[p] = (unsigned int)s | ((unsigned int)(d & 255) << 16);
        }
    }
}

// per-bucket LDS counting sort; also emits dinv[n]=rsqrt(deg)
__global__ void bucket_sort(const unsigned int* __restrict__ ebuf, const int* __restrict__ cmat,
                            int* __restrict__ row_start, unsigned short* __restrict__ csr16,
                            float* __restrict__ dinv) {
    __shared__ unsigned int earr[BCAP];
    __shared__ unsigned short out16[BCAP];
    __shared__ int ecnt[256], epre[256];
    const int t = threadIdx.x, g = blockIdx.x;
    const int bstart = cmat[g * NBE];
    const int bend = (g == NBUCK - 1) ? EP : cmat[(g + 1) * NBE];
    const int m = bend - bstart;
    ecnt[t] = 0;
    __syncthreads();
    for (int i = t; i < m; i += 256) {
        const unsigned int v = ebuf[bstart + i];
        earr[i] = v;
        atomicAdd(&ecnt[v >> 16], 1);
    }
    __syncthreads();
    const int v0 = ecnt[t];
    epre[t] = v0;
    __syncthreads();
    for (int o = 1; o < 256; o <<= 1) {
        const int u = (t >= o) ? epre[t - o] : 0;
        __syncthreads();
        epre[t] += u;
        __syncthreads();
    }
    const int my_excl = epre[t] - v0;
    const int n = g * 256 + t;
    if (n <= NN) row_start[n] = bstart + my_excl;
    if (n < NN) dinv[n] = rsqrtf((float)v0);   // deg >= 1 (self loop)
    ecnt[t] = my_excl;
    __syncthreads();
    for (int i = t; i < m; i += 256) {
        const unsigned int v = earr[i];
        const int p = atomicAdd(&ecnt[v >> 16], 1);
        out16[p] = (unsigned short)(v & 0xffffu);
    }
    __syncthreads();
    for (int i = t; i < m; i += 256) csr16[bstart + i] = out16[i];
}

// ---- GAT gather (R13-proven): one wave/node, 16 lanes/edge over 256B rows,
// 4 edges per issue group, dual accumulators.
__global__ void gat_gather(const int* __restrict__ row_start, const unsigned short* __restrict__ csr_src,
                           const float* __restrict__ asrc, const float* __restrict__ adst,
                           const unsigned short* __restrict__ hb, const float* __restrict__ bias,
                           unsigned short* __restrict__ out) {
    const int n = blockIdx.x * 4 + (threadIdx.x >> 6);
    const int lane = threadIdx.x & 63;
    if (n >= NN) return;
    const int quarter = lane >> 4;
    const int qo = (lane & 15) << 3;
    const int lo = row_start[n], hi = row_start[n + 1];
    const float adn = adst[n];
    float den = 0.f;
    float accA[8] = {}, accB[8] = {};
    for (int base = lo; base < hi; base += 64) {
        const int cnt = min(64, hi - base);
        const int sv = (lane < cnt) ? (int)csr_src[base + lane] : 0;
        float ev = 0.f;
        if (lane < cnt) {
            float sc = asrc[sv] + adn;
            sc = sc > 0.f ? sc : 0.2f * sc;
            ev = __expf(sc);
        }
        den += ev;
        int j = 0;
        for (; j + 16 <= cnt; j += 16) {
#pragma unroll
            for (int t = 0; t < 4; ++t) {
                const int jj = j + 4 * t + quarter;
                const int   s = __shfl(sv, jj);
                const float w = __shfl(ev, jj);
                const uint4 hv = *(const uint4*)(hb + (size_t)s * F + qo);
                bf8_fma((t & 1) ? accB : accA, w, hv);
            }
        }
        for (; j < cnt; j += 4) {       // jj <= 63; ev=0 pads beyond cnt
            const int jj = j + quarter;
            const int   s = __shfl(sv, jj);
            const float w = __shfl(ev, jj);
            const uint4 hv = *(const uint4*)(hb + (size_t)s * F + qo);
            bf8_fma(accA, w, hv);
        }
    }
    float acc[8];
#pragma unroll
    for (int i = 0; i < 8; ++i) {
        float v = accA[i] + accB[i];
        v += __shfl_xor(v, 16);
        v += __shfl_xor(v, 32);
        acc[i] = v;
    }
    for (int o = 32; o; o >>= 1) den += __shfl_xor(den, o);
    const float inv = 1.f / den;        // den > 0 (self loop)
    if (lane < 16) {
        float v[8];
#pragma unroll
        for (int i = 0; i < 8; ++i) {
            v[i] = fmaf(acc[i], inv, bias[qo + i]);
            v[i] = v[i] > 0.f ? v[i] : 0.f;
        }
        uint4 pk;
        pk.x = pack2(v[0], v[1]); pk.y = pack2(v[2], v[3]);
        pk.z = pack2(v[4], v[5]); pk.w = pack2(v[6], v[7]);
        *(uint4*)(out + (size_t)n * F + qo) = pk;
    }
}

// ---- GCN gather (R13-proven) + fused mean-pool/head partials.
__global__ void gcn_gather_pool(const int* __restrict__ row_start, const unsigned short* __restrict__ csr_src,
                                const float* __restrict__ dinv, const unsigned short* __restrict__ hb,
                                const float* __restrict__ bias, const int* __restrict__ batch,
                                const float* __restrict__ Wf, float* __restrict__ gscr) {
    __shared__ int   sg[4];
    __shared__ float sp0[4], sp1[4];
    const int wave = threadIdx.x >> 6;
    const int n = blockIdx.x * 4 + wave;
    const int lane = threadIdx.x & 63;
    const int quarter = lane >> 4;
    const int qo = (lane & 15) << 3;
    if (threadIdx.x < 4) sg[threadIdx.x] = -1;
    float p0 = 0.f, p1 = 0.f;
    if (n < NN) {
        const int lo = row_start[n], hi = row_start[n + 1];
        const float dn = dinv[n];
        float accA[8] = {}, accB[8] = {};
        for (int base = lo; base < hi; base += 64) {
            const int cnt = min(64, hi - base);
            const int sv = (lane < cnt) ? (int)csr_src[base + lane] : 0;
            const float wv = (lane < cnt) ? dinv[sv] : 0.f;
            int j = 0;
            for (; j + 16 <= cnt; j += 16) {
#pragma unroll
                for (int t = 0; t < 4; ++t) {
                    const int jj = j + 4 * t + quarter;
                    const int   s = __shfl(sv, jj);
                    const float w = __shfl(wv, jj);
                    const uint4 hv = *(const uint4*)(hb + (size_t)s * F + qo);
                    bf8_fma((t & 1) ? accB : accA, w, hv);
                }
            }
            for (; j < cnt; j += 4) {
                const int jj = j + quarter;
                const int   s = __shfl(sv, jj);
                const float w = __shfl(wv, jj);
                const uint4 hv = *(const uint4*)(hb + (size_t)s * F + qo);
                bf8_fma(accA, w, hv);
            }
        }
        float v[8];
#pragma unroll
        for (int i = 0; i < 8; ++i) {
            float a = accA[i] + accB[i];
            a += __shfl_xor(a, 16);
            a += __shfl_xor(a, 32);
            v[i] = fmaf(a, dn, bias[qo + i]);
            v[i] = v[i] > 0.f ? v[i] : 0.f;
        }
        const float4 w0 = *(const float4*)(Wf + qo * 2);
        const float4 w1 = *(const float4*)(Wf + qo * 2 + 4);
        const float4 w2 = *(const float4*)(Wf + qo * 2 + 8);
        const float4 w3 = *(const float4*)(Wf + qo * 2 + 12);
        p0 = v[0]*w0.x + v[1]*w0.z + v[2]*w1.x + v[3]*w1.z +
             v[4]*w2.x + v[5]*w2.z + v[6]*w3.x + v[7]*w3.z;
        p1 = v[0]*w0.y + v[1]*w0.w + v[2]*w1.y + v[3]*w1.w +
             v[4]*w2.y + v[5]*w2.w + v[6]*w3.y + v[7]*w3.w;
        for (int o = 8; o; o >>= 1) { p0 += __shfl_xor(p0, o); p1 += __shfl_xor(p1, o); }
    }
    if (lane == 0 && n < NN) { sg[wave] = batch[n]; sp0[wave] = p0; sp1[wave] = p1; }
    __syncthreads();
    if (threadIdx.x == 0) {
#pragma unroll
        for (int w = 0; w < 4; ++w) {
            const int g = sg[w];
            if (g < 0) continue;
            float q0 = sp0[w], q1 = sp1[w];
            for (int u = w + 1; u < 4; ++u) {
                if (sg[u] == g) { q0 += sp0[u]; q1 += sp1[u]; sg[u] = -1; }
            }
            atomicAdd(gscr + g * 32,     q0);
            atomicAdd(gscr + g * 32 + 1, q1);
        }
    }
}

__global__ void finalize(const float* __restrict__ gscr, const int* __restrict__ batch,
                         const float* __restrict__ bf, float* __restrict__ out) {
    const int g = threadIdx.x;   // 128
    int lo = 0, hi = NN;
    while (lo < hi) { int m = (lo + hi) >> 1; if (batch[m] < g) lo = m + 1; else hi = m; }
    int lo2 = lo, hi2 = NN;
    while (lo2 < hi2) { int m = (lo2 + hi2) >> 1; if (batch[m] < g + 1) lo2 = m + 1; else hi2 = m; }
    const float inv = 1.f / fmaxf((float)(lo2 - lo), 1.f);
    out[g * 2]     = gscr[g * 32]     * inv + bf[0];
    out[g * 2 + 1] = gscr[g * 32 + 1] * inv + bf[1];
}

extern "C" void kernel_launch(void* const* d_in, const int* in_sizes, int n_in,
                              void* d_out, int out_size, void* d_ws, size_t ws_size,
                              hipStream_t stream) {
    const float* x       = (const float*)d_in[0];
    const float* W1      = (const float*)d_in[1];
    const float* att_src = (const float*)d_in[2];
    const float* att_dst = (const float*)d_in[3];
    const float* b1      = (const float*)d_in[4];
    const float* W2      = (const float*)d_in[5];
    const float* b2      = (const float*)d_in[6];
    const float* Wf      = (const float*)d_in[7];
    const float* bf      = (const float*)d_in[8];
    const int*   ei      = (const int*)d_in[9];
    const int*   batch   = (const int*)d_in[10];
    float* out = (float*)d_out;

    unsigned short* h1b  = (unsigned short*)d_ws;                   // [NN*F] bf16 gemm1 out
    unsigned short* hgb  = h1b + (size_t)NN * F;                    // [NN*F] bf16 GAT out
    unsigned short* h2b  = hgb + (size_t)NN * F;                    // [NN*F] bf16 gemm2 out
    float* asrc      = (float*)(h2b + (size_t)NN * F);              // [NN]
    float* adst      = asrc + NN;                                   // [NN]
    float* dinv      = adst + NN;                                   // [NN]
    float* gscr      = dinv + NN;                                   // [NG*32]
    int*   row_start = (int*)(gscr + NG * 32);                      // [NN+1]
    unsigned short* csr16 = (unsigned short*)(row_start + NN + 1);  // [EP]
    unsigned int*   ebuf  = (unsigned int*)(csr16 + EP);            // [EP]
    int*   cmat      = (int*)(ebuf + EP);                           // [CMAT]
    uint4* wf1       = (uint4*)(cmat + CMAT);                       // [2048] W1 frags
    uint4* wf2       = wf1 + 2048;                                  // [2048] W2 frags

    // one-shot weight packing + CSR build (gscr zeroed inside bin_count)
    pack_wfrag2<<<16, 256, 0, stream>>>(W1, W2, wf1);
    bin_count<<<NBE, 256, 0, stream>>>(ei, cmat, gscr);
    scan_all<<<1, 1024, 0, stream>>>(cmat);
    bin_scatter<<<NBE, 256, 0, stream>>>(ei, cmat, ebuf);
    bucket_sort<<<NBUCK, 256, 0, stream>>>(ebuf, cmat, row_start, csr16, dinv);

    mfma_gemm<<<(NN + 63) / 64, 256, 0, stream>>>(nullptr, x, wf1, h1b, NN,
                                                  att_src, att_dst, asrc, adst);
    gat_gather<<<(NN + 3) / 4, 256, 0, stream>>>(row_start, csr16, asrc, adst, h1b, b1, hgb);
    mfma_gemm<<<(NN + 63) / 64, 256, 0, stream>>>(hgb, nullptr, wf2, h2b, NN,
                                                  nullptr, nullptr, nullptr, nullptr);
    gcn_gather_pool<<<(NN + 3) / 4, 256, 0, stream>>>(row_start, csr16, dinv, h2b, b2,
                                                      batch, Wf, gscr);
    finalize<<<1, NG, 0, stream>>>(gscr, batch, bf, out);
}

// Round 16
// 227.910 us; speedup vs baseline: 1.6860x; 1.1846x over previous
//
#include <hip/hip_runtime.h>

#define NN 50000
#define NE 800000
#define EP (NE + NN)      // edges + self loops = 850000
#define NG 128
#define F 128
#define NBE 208           // edge-pass blocks
#define EPB 4096          // edges per block (208*4096 >= EP)
#define NBUCK 196         // dst buckets of 256 nodes
#define BCAP 6144         // per-bucket edge cap (mean 4352, max ~4650)

typedef __attribute__((ext_vector_type(8))) short short8;
typedef __attribute__((ext_vector_type(4))) float float4v;
union U8 { uint4 u; short8 s; };

__device__ inline unsigned int bf16rn(float x) {   // RNE round to bf16 (low 16 bits)
    unsigned int u = __float_as_uint(x);
    u += 0x7fffu + ((u >> 16) & 1u);
    return u >> 16;
}
__device__ inline unsigned int pack2(float a, float b) {
    return bf16rn(a) | (bf16rn(b) << 16);
}
// 8 bf16 (uint4) -> 8 fma's into acc[0..7]
__device__ inline void bf8_fma(float* acc, float w, uint4 hv) {
    acc[0] = fmaf(w, __uint_as_float(hv.x << 16), acc[0]);
    acc[1] = fmaf(w, __uint_as_float(hv.x & 0xffff0000u), acc[1]);
    acc[2] = fmaf(w, __uint_as_float(hv.y << 16), acc[2]);
    acc[3] = fmaf(w, __uint_as_float(hv.y & 0xffff0000u), acc[3]);
    acc[4] = fmaf(w, __uint_as_float(hv.z << 16), acc[4]);
    acc[5] = fmaf(w, __uint_as_float(hv.z & 0xffff0000u), acc[5]);
    acc[6] = fmaf(w, __uint_as_float(hv.w << 16), acc[6]);
    acc[7] = fmaf(w, __uint_as_float(hv.w & 0xffff0000u), acc[7]);
}

// One-shot: pack W1 and W2 fp32 [128][128] into MFMA B-fragments (bf16).
// Also zeroes gscr (block 16) and cnt (block 16) — both written much later.
__global__ void pack_wfrag2(const float* __restrict__ W1, const float* __restrict__ W2,
                            uint4* __restrict__ wf, float* __restrict__ gscr,
                            int* __restrict__ cnt) {
    const int p = blockIdx.x * blockDim.x + threadIdx.x;   // 0..4351
    if (p >= 4096) {                    // block 16: zero gscr + cnt
        const int t = threadIdx.x;
        for (int i = t; i < NG * 32; i += 256) gscr[i] = 0.f;
        for (int i = t; i < NBUCK; i += 256) cnt[i] = 0;
        return;
    }
    const float* W = (p < 2048) ? W1 : W2;
    const int q = p & 2047;
    const int f = q >> 6, l = q & 63;
    const int kt = f >> 3, nt = f & 7;
    const int rb = kt * 32 + ((l >> 4) << 3);
    const int col = nt * 16 + (l & 15);
    const float* wp = W + (size_t)rb * F + col;
    uint4 pk;
    pk.x = pack2(wp[0],     wp[F]);
    pk.y = pack2(wp[2 * F], wp[3 * F]);
    pk.z = pack2(wp[4 * F], wp[5 * F]);
    pk.w = pack2(wp[6 * F], wp[7 * F]);
    wf[p] = pk;
}

// C[N,128] = A[N,128] @ W via v_mfma_f32_16x16x32_bf16. No LDS, no barriers:
// B-fragments pre-packed in global (32 KB, L2-broadcast). 4 waves = 64 rows/block.
// A read either as bf16 (Ab) or fp32 (Af, converted in-register; gemm1 path).
__global__ __launch_bounds__(256) void mfma_gemm(
        const unsigned short* __restrict__ Ab, const float* __restrict__ Af,
        const uint4* __restrict__ wf,
        unsigned short* __restrict__ Cb, int N,
        const float* __restrict__ att_src, const float* __restrict__ att_dst,
        float* __restrict__ asrc, float* __restrict__ adst) {
    const int t = threadIdx.x;
    const int wave = t >> 6, lane = t & 63;
    const int m0 = blockIdx.x * 64 + wave * 16;
    const int arow = m0 + (lane & 15);
    const int kq = (lane >> 4) << 3;
    U8 a[4];
#pragma unroll
    for (int kt = 0; kt < 4; ++kt) {
        if (arow < N) {
            if (Af) {
                const float* ap = Af + (size_t)arow * F + kt * 32 + kq;
                const float4 f0 = *(const float4*)ap;
                const float4 f1 = *(const float4*)(ap + 4);
                a[kt].u = make_uint4(pack2(f0.x, f0.y), pack2(f0.z, f0.w),
                                     pack2(f1.x, f1.y), pack2(f1.z, f1.w));
            } else {
                a[kt].u = *(const uint4*)(Ab + (size_t)arow * F + kt * 32 + kq);
            }
        } else {
            a[kt].u = make_uint4(0, 0, 0, 0);
        }
    }
    const int ccol = lane & 15;
    const int crow0 = m0 + ((lane >> 4) << 2);
    float ps[4] = {}, pd[4] = {};
    for (int nt = 0; nt < 8; nt += 2) {
        float4v acc0 = {0.f, 0.f, 0.f, 0.f}, acc1 = {0.f, 0.f, 0.f, 0.f};
#pragma unroll
        for (int kt = 0; kt < 4; ++kt) {
            U8 b0, b1;
            b0.u = wf[(kt * 8 + nt) * 64 + lane];
            b1.u = wf[(kt * 8 + nt + 1) * 64 + lane];
            acc0 = __builtin_amdgcn_mfma_f32_16x16x32_bf16(a[kt].s, b0.s, acc0, 0, 0, 0);
            acc1 = __builtin_amdgcn_mfma_f32_16x16x32_bf16(a[kt].s, b1.s, acc1, 0, 0, 0);
        }
#pragma unroll
        for (int r = 0; r < 4; ++r) {
            const int row = crow0 + r;
            if (row < N) {
                Cb[(size_t)row * F + nt * 16 + ccol]       = (unsigned short)bf16rn(acc0[r]);
                Cb[(size_t)row * F + (nt + 1) * 16 + ccol] = (unsigned short)bf16rn(acc1[r]);
            }
        }
        if (asrc) {
            const float as0 = att_src[nt * 16 + ccol], as1 = att_src[(nt + 1) * 16 + ccol];
            const float ad0 = att_dst[nt * 16 + ccol], ad1 = att_dst[(nt + 1) * 16 + ccol];
#pragma unroll
            for (int r = 0; r < 4; ++r) {
                ps[r] += acc0[r] * as0 + acc1[r] * as1;
                pd[r] += acc0[r] * ad0 + acc1[r] * ad1;
            }
        }
    }
    if (asrc) {
#pragma unroll
        for (int r = 0; r < 4; ++r) {
            float s = ps[r], d = pd[r];
#pragma unroll
            for (int o = 8; o; o >>= 1) { s += __shfl_xor(s, o); d += __shfl_xor(d, o); }
            const int row = crow0 + r;
            if (ccol == 0 && row < N) { asrc[row] = s; adst[row] = d; }
        }
    }
}

// ---- Fused CSR bucket scatter: per-block LDS histogram -> one global range
// reservation per (bucket,block) -> scatter into fixed per-bucket regions.
// Replaces bin_count + scan_all + bin_scatter (order within bucket is
// nondeterministic; only permutes fp summation order downstream).
__global__ void count_scatter(const int* __restrict__ ei, int* __restrict__ cur,
                              unsigned int* __restrict__ ebuf) {
    __shared__ int lcnt[NBUCK];
    __shared__ int lbase[NBUCK];
    const int t = threadIdx.x, b = blockIdx.x;
    for (int i = t; i < NBUCK; i += 256) lcnt[i] = 0;
    __syncthreads();
    const int e0 = b * EPB;
    int sarr[EPB / 256], darr[EPB / 256];
#pragma unroll
    for (int i = 0; i < EPB / 256; ++i) {
        const int e = e0 + i * 256 + t;
        int s = 0, d = -1;
        if (e < EP) {
            if (e < NE) { s = ei[e]; d = ei[NE + e]; } else { s = d = e - NE; }
            atomicAdd(&lcnt[d >> 8], 1);
        }
        sarr[i] = s; darr[i] = d;
    }
    __syncthreads();
    for (int i = t; i < NBUCK; i += 256) {
        lbase[i] = atomicAdd(&cur[i], lcnt[i]);   // reserve contiguous run
        lcnt[i] = 0;                              // reuse as local cursor
    }
    __syncthreads();
#pragma unroll
    for (int i = 0; i < EPB / 256; ++i) {
        const int d = darr[i];
        if (d >= 0) {
            const int bk = d >> 8;
            const int p = lbase[bk] + atomicAdd(&lcnt[bk], 1);
            ebuf[(size_t)bk * BCAP + p] = (unsigned int)sarr[i] | ((unsigned int)(d & 255) << 16);
        }
    }
}

// per-bucket LDS counting sort from fixed regions; emits row_start, deg, dinv,
// csr16 (also in fixed per-bucket regions: row_start[n] = g*BCAP + prefix).
__global__ void bucket_sort(const unsigned int* __restrict__ ebuf, const int* __restrict__ cnt,
                            int* __restrict__ row_start, unsigned short* __restrict__ csr16,
                            int* __restrict__ deg, float* __restrict__ dinv) {
    __shared__ unsigned int earr[BCAP];
    __shared__ unsigned short out16[BCAP];
    __shared__ int ecnt[256], epre[256];
    const int t = threadIdx.x, g = blockIdx.x;
    const int m = cnt[g];
    const unsigned int* src = ebuf + (size_t)g * BCAP;
    ecnt[t] = 0;
    __syncthreads();
    for (int i = t; i < m; i += 256) {
        const unsigned int v = src[i];
        earr[i] = v;
        atomicAdd(&ecnt[v >> 16], 1);
    }
    __syncthreads();
    const int v0 = ecnt[t];
    epre[t] = v0;
    __syncthreads();
    for (int o = 1; o < 256; o <<= 1) {
        const int u = (t >= o) ? epre[t - o] : 0;
        __syncthreads();
        epre[t] += u;
        __syncthreads();
    }
    const int my_excl = epre[t] - v0;
    const int n = g * 256 + t;
    if (n < NN) {
        row_start[n] = g * BCAP + my_excl;
        deg[n] = v0;                               // >= 1 (self loop)
        dinv[n] = rsqrtf((float)v0);
    }
    ecnt[t] = my_excl;
    __syncthreads();
    for (int i = t; i < m; i += 256) {
        const unsigned int v = earr[i];
        const int p = atomicAdd(&ecnt[v >> 16], 1);
        out16[p] = (unsigned short)(v & 0xffffu);
    }
    __syncthreads();
    unsigned short* dst = csr16 + (size_t)g * BCAP;
    for (int i = t; i < m; i += 256) dst[i] = out16[i];
}

// ---- GAT gather (R13-proven): one wave/node, 16 lanes/edge over 256B rows,
// 4 edges per issue group, dual accumulators.
__global__ void gat_gather(const int* __restrict__ row_start, const int* __restrict__ deg,
                           const unsigned short* __restrict__ csr_src,
                           const float* __restrict__ asrc, const float* __restrict__ adst,
                           const unsigned short* __restrict__ hb, const float* __restrict__ bias,
                           unsigned short* __restrict__ out) {
    const int n = blockIdx.x * 4 + (threadIdx.x >> 6);
    const int lane = threadIdx.x & 63;
    if (n >= NN) return;
    const int quarter = lane >> 4;
    const int qo = (lane & 15) << 3;
    const int lo = row_start[n], hi = lo + deg[n];
    const float adn = adst[n];
    float den = 0.f;
    float accA[8] = {}, accB[8] = {};
    for (int base = lo; base < hi; base += 64) {
        const int cnt = min(64, hi - base);
        const int sv = (lane < cnt) ? (int)csr_src[base + lane] : 0;
        float ev = 0.f;
        if (lane < cnt) {
            float sc = asrc[sv] + adn;
            sc = sc > 0.f ? sc : 0.2f * sc;
            ev = __expf(sc);
        }
        den += ev;
        int j = 0;
        for (; j + 16 <= cnt; j += 16) {
#pragma unroll
            for (int t = 0; t < 4; ++t) {
                const int jj = j + 4 * t + quarter;
                const int   s = __shfl(sv, jj);
                const float w = __shfl(ev, jj);
                const uint4 hv = *(const uint4*)(hb + (size_t)s * F + qo);
                bf8_fma((t & 1) ? accB : accA, w, hv);
            }
        }
        for (; j < cnt; j += 4) {       // jj <= 63; ev=0 pads beyond cnt
            const int jj = j + quarter;
            const int   s = __shfl(sv, jj);
            const float w = __shfl(ev, jj);
            const uint4 hv = *(const uint4*)(hb + (size_t)s * F + qo);
            bf8_fma(accA, w, hv);
        }
    }
    float acc[8];
#pragma unroll
    for (int i = 0; i < 8; ++i) {
        float v = accA[i] + accB[i];
        v += __shfl_xor(v, 16);
        v += __shfl_xor(v, 32);
        acc[i] = v;
    }
    for (int o = 32; o; o >>= 1) den += __shfl_xor(den, o);
    const float inv = 1.f / den;        // den > 0 (self loop)
    if (lane < 16) {
        float v[8];
#pragma unroll
        for (int i = 0; i < 8; ++i) {
            v[i] = fmaf(acc[i], inv, bias[qo + i]);
            v[i] = v[i] > 0.f ? v[i] : 0.f;
        }
        uint4 pk;
        pk.x = pack2(v[0], v[1]); pk.y = pack2(v[2], v[3]);
        pk.z = pack2(v[4], v[5]); pk.w = pack2(v[6], v[7]);
        *(uint4*)(out + (size_t)n * F + qo) = pk;
    }
}

// ---- GCN gather (R13-proven) + fused mean-pool/head partials.
__global__ void gcn_gather_pool(const int* __restrict__ row_start, const int* __restrict__ deg,
                                const unsigned short* __restrict__ csr_src,
                                const float* __restrict__ dinv, const unsigned short* __restrict__ hb,
                                const float* __restrict__ bias, const int* __restrict__ batch,
                                const float* __restrict__ Wf, float* __restrict__ gscr) {
    __shared__ int   sg[4];
    __shared__ float sp0[4], sp1[4];
    const int wave = threadIdx.x >> 6;
    const int n = blockIdx.x * 4 + wave;
    const int lane = threadIdx.x & 63;
    const int quarter = lane >> 4;
    const int qo = (lane & 15) << 3;
    if (threadIdx.x < 4) sg[threadIdx.x] = -1;
    float p0 = 0.f, p1 = 0.f;
    if (n < NN) {
        const int lo = row_start[n], hi = lo + deg[n];
        const float dn = dinv[n];
        float accA[8] = {}, accB[8] = {};
        for (int base = lo; base < hi; base += 64) {
            const int cnt = min(64, hi - base);
            const int sv = (lane < cnt) ? (int)csr_src[base + lane] : 0;
            const float wv = (lane < cnt) ? dinv[sv] : 0.f;
            int j = 0;
            for (; j + 16 <= cnt; j += 16) {
#pragma unroll
                for (int t = 0; t < 4; ++t) {
                    const int jj = j + 4 * t + quarter;
                    const int   s = __shfl(sv, jj);
                    const float w = __shfl(wv, jj);
                    const uint4 hv = *(const uint4*)(hb + (size_t)s * F + qo);
                    bf8_fma((t & 1) ? accB : accA, w, hv);
                }
            }
            for (; j < cnt; j += 4) {
                const int jj = j + quarter;
                const int   s = __shfl(sv, jj);
                const float w = __shfl(wv, jj);
                const uint4 hv = *(const uint4*)(hb + (size_t)s * F + qo);
                bf8_fma(accA, w, hv);
            }
        }
        float v[8];
#pragma unroll
        for (int i = 0; i < 8; ++i) {
            float a = accA[i] + accB[i];
            a += __shfl_xor(a, 16);
            a += __shfl_xor(a, 32);
            v[i] = fmaf(a, dn, bias[qo + i]);
            v[i] = v[i] > 0.f ? v[i] : 0.f;
        }
        const float4 w0 = *(const float4*)(Wf + qo * 2);
        const float4 w1 = *(const float4*)(Wf + qo * 2 + 4);
        const float4 w2 = *(const float4*)(Wf + qo * 2 + 8);
        const float4 w3 = *(const float4*)(Wf + qo * 2 + 12);
        p0 = v[0]*w0.x + v[1]*w0.z + v[2]*w1.x + v[3]*w1.z +
             v[4]*w2.x + v[5]*w2.z + v[6]*w3.x + v[7]*w3.z;
        p1 = v[0]*w0.y + v[1]*w0.w + v[2]*w1.y + v[3]*w1.w +
             v[4]*w2.y + v[5]*w2.w + v[6]*w3.y + v[7]*w3.w;
        for (int o = 8; o; o >>= 1) { p0 += __shfl_xor(p0, o); p1 += __shfl_xor(p1, o); }
    }
    if (lane == 0 && n < NN) { sg[wave] = batch[n]; sp0[wave] = p0; sp1[wave] = p1; }
    __syncthreads();
    if (threadIdx.x == 0) {
#pragma unroll
        for (int w = 0; w < 4; ++w) {
            const int g = sg[w];
            if (g < 0) continue;
            float q0 = sp0[w], q1 = sp1[w];
            for (int u = w + 1; u < 4; ++u) {
                if (sg[u] == g) { q0 += sp0[u]; q1 += sp1[u]; sg[u] = -1; }
            }
            atomicAdd(gscr + g * 32,     q0);
            atomicAdd(gscr + g * 32 + 1, q1);
        }
    }
}

__global__ void finalize(const float* __restrict__ gscr, const int* __restrict__ batch,
                         const float* __restrict__ bf, float* __restrict__ out) {
    const int g = threadIdx.x;   // 128
    int lo = 0, hi = NN;
    while (lo < hi) { int m = (lo + hi) >> 1; if (batch[m] < g) lo = m + 1; else hi = m; }
    int lo2 = lo, hi2 = NN;
    while (lo2 < hi2) { int m = (lo2 + hi2) >> 1; if (batch[m] < g + 1) lo2 = m + 1; else hi2 = m; }
    const float inv = 1.f / fmaxf((float)(lo2 - lo), 1.f);
    out[g * 2]     = gscr[g * 32]     * inv + bf[0];
    out[g * 2 + 1] = gscr[g * 32 + 1] * inv + bf[1];
}

extern "C" void kernel_launch(void* const* d_in, const int* in_sizes, int n_in,
                              void* d_out, int out_size, void* d_ws, size_t ws_size,
                              hipStream_t stream) {
    const float* x       = (const float*)d_in[0];
    const float* W1      = (const float*)d_in[1];
    const float* att_src = (const float*)d_in[2];
    const float* att_dst = (const float*)d_in[3];
    const float* b1      = (const float*)d_in[4];
    const float* W2      = (const float*)d_in[5];
    const float* b2      = (const float*)d_in[6];
    const float* Wf      = (const float*)d_in[7];
    const float* bf      = (const float*)d_in[8];
    const int*   ei      = (const int*)d_in[9];
    const int*   batch   = (const int*)d_in[10];
    float* out = (float*)d_out;

    unsigned short* h1b  = (unsigned short*)d_ws;                   // [NN*F] bf16 gemm1 out
    unsigned short* hgb  = h1b + (size_t)NN * F;                    // [NN*F] bf16 GAT out
    unsigned short* h2b  = hgb + (size_t)NN * F;                    // [NN*F] bf16 gemm2 out
    float* asrc      = (float*)(h2b + (size_t)NN * F);              // [NN]
    float* adst      = asrc + NN;                                   // [NN]
    float* dinv      = adst + NN;                                   // [NN]
    float* gscr      = dinv + NN;                                   // [NG*32]
    int*   row_start = (int*)(gscr + NG * 32);                      // [NN]
    int*   deg       = row_start + NN;                              // [NN]
    int*   cnt       = deg + NN;                                    // [NBUCK]
    unsigned short* csr16 = (unsigned short*)(cnt + NBUCK);         // [NBUCK*BCAP]
    unsigned int*   ebuf  = (unsigned int*)(csr16 + (size_t)NBUCK * BCAP); // [NBUCK*BCAP]
    uint4* wf1       = (uint4*)(ebuf + (size_t)NBUCK * BCAP);       // [2048] W1 frags
    uint4* wf2       = wf1 + 2048;                                  // [2048] W2 frags

    // one-shot weight packing (+ gscr/cnt zeroing) + fused CSR build
    pack_wfrag2<<<17, 256, 0, stream>>>(W1, W2, wf1, gscr, cnt);
    count_scatter<<<NBE, 256, 0, stream>>>(ei, cnt, ebuf);
    bucket_sort<<<NBUCK, 256, 0, stream>>>(ebuf, cnt, row_start, csr16, deg, dinv);

    mfma_gemm<<<(NN + 63) / 64, 256, 0, stream>>>(nullptr, x, wf1, h1b, NN,
                                                  att_src, att_dst, asrc, adst);
    gat_gather<<<(NN + 3) / 4, 256, 0, stream>>>(row_start, deg, csr16, asrc, adst,
                                                 h1b, b1, hgb);
    mfma_gemm<<<(NN + 63) / 64, 256, 0, stream>>>(hgb, nullptr, wf2, h2b, NN,
                                                  nullptr, nullptr, nullptr, nullptr);
    gcn_gather_pool<<<(NN + 3) / 4, 256, 0, stream>>>(row_start, deg, csr16, dinv, h2b, b2,
                                                      batch, Wf, gscr);
    finalize<<<1, NG, 0, stream>>>(gscr, batch, bf, out);
}

// Round 17
// 226.590 us; speedup vs baseline: 1.6958x; 1.0058x over previous
//
#include <hip/hip_runtime.h>

#define NN 50000
#define NE 800000
#define EP (NE + NN)      // edges + self loops = 850000
#define NG 128
#define F 128
#define NBE 208           // edge-pass blocks
#define EPB 4096          // edges per block (208*4096 >= EP)
#define NBUCK 196         // dst buckets of 256 nodes
#define BCAP 6144         // per-bucket edge cap (mean 4352, max ~4650)

typedef __attribute__((ext_vector_type(8))) short short8;
typedef __attribute__((ext_vector_type(4))) float float4v;
union U8 { uint4 u; short8 s; };

__device__ inline unsigned int bf16rn(float x) {   // RNE round to bf16 (low 16 bits)
    unsigned int u = __float_as_uint(x);
    u += 0x7fffu + ((u >> 16) & 1u);
    return u >> 16;
}
__device__ inline unsigned int pack2(float a, float b) {
    return bf16rn(a) | (bf16rn(b) << 16);
}
// 8 bf16 (uint4) -> 8 fma's into acc[0..7]
__device__ inline void bf8_fma(float* acc, float w, uint4 hv) {
    acc[0] = fmaf(w, __uint_as_float(hv.x << 16), acc[0]);
    acc[1] = fmaf(w, __uint_as_float(hv.x & 0xffff0000u), acc[1]);
    acc[2] = fmaf(w, __uint_as_float(hv.y << 16), acc[2]);
    acc[3] = fmaf(w, __uint_as_float(hv.y & 0xffff0000u), acc[3]);
    acc[4] = fmaf(w, __uint_as_float(hv.z << 16), acc[4]);
    acc[5] = fmaf(w, __uint_as_float(hv.z & 0xffff0000u), acc[5]);
    acc[6] = fmaf(w, __uint_as_float(hv.w << 16), acc[6]);
    acc[7] = fmaf(w, __uint_as_float(hv.w & 0xffff0000u), acc[7]);
}
// 8 bf16 (uint4) -> 8 plain adds into acc[0..7] (pre-scaled rows)
__device__ inline void bf8_add(float* acc, uint4 hv) {
    acc[0] += __uint_as_float(hv.x << 16);
    acc[1] += __uint_as_float(hv.x & 0xffff0000u);
    acc[2] += __uint_as_float(hv.y << 16);
    acc[3] += __uint_as_float(hv.y & 0xffff0000u);
    acc[4] += __uint_as_float(hv.z << 16);
    acc[5] += __uint_as_float(hv.z & 0xffff0000u);
    acc[6] += __uint_as_float(hv.w << 16);
    acc[7] += __uint_as_float(hv.w & 0xffff0000u);
}

// One-shot: pack W1 and W2 fp32 [128][128] into MFMA B-fragments (bf16).
// Also zeroes gscr (block 16) and cnt (block 16) — both written much later.
__global__ void pack_wfrag2(const float* __restrict__ W1, const float* __restrict__ W2,
                            uint4* __restrict__ wf, float* __restrict__ gscr,
                            int* __restrict__ cnt) {
    const int p = blockIdx.x * blockDim.x + threadIdx.x;   // 0..4351
    if (p >= 4096) {                    // block 16: zero gscr + cnt
        const int t = threadIdx.x;
        for (int i = t; i < NG * 32; i += 256) gscr[i] = 0.f;
        for (int i = t; i < NBUCK; i += 256) cnt[i] = 0;
        return;
    }
    const float* W = (p < 2048) ? W1 : W2;
    const int q = p & 2047;
    const int f = q >> 6, l = q & 63;
    const int kt = f >> 3, nt = f & 7;
    const int rb = kt * 32 + ((l >> 4) << 3);
    const int col = nt * 16 + (l & 15);
    const float* wp = W + (size_t)rb * F + col;
    uint4 pk;
    pk.x = pack2(wp[0],     wp[F]);
    pk.y = pack2(wp[2 * F], wp[3 * F]);
    pk.z = pack2(wp[4 * F], wp[5 * F]);
    pk.w = pack2(wp[6 * F], wp[7 * F]);
    wf[p] = pk;
}

// C[N,128] = A[N,128] @ W via v_mfma_f32_16x16x32_bf16. No LDS, no barriers.
// A read either as bf16 (Ab) or fp32 (Af, converted in-register; gemm1 path).
// Optional row_scale: C row r scaled by row_scale[r] before bf16 pack
// (gemm2 path: folds dinv[s] into h2 rows so the GCN gather needs no weight).
__global__ __launch_bounds__(256) void mfma_gemm(
        const unsigned short* __restrict__ Ab, const float* __restrict__ Af,
        const uint4* __restrict__ wf,
        unsigned short* __restrict__ Cb, int N,
        const float* __restrict__ att_src, const float* __restrict__ att_dst,
        float* __restrict__ asrc, float* __restrict__ adst,
        const float* __restrict__ row_scale) {
    const int t = threadIdx.x;
    const int wave = t >> 6, lane = t & 63;
    const int m0 = blockIdx.x * 64 + wave * 16;
    const int arow = m0 + (lane & 15);
    const int kq = (lane >> 4) << 3;
    U8 a[4];
#pragma unroll
    for (int kt = 0; kt < 4; ++kt) {
        if (arow < N) {
            if (Af) {
                const float* ap = Af + (size_t)arow * F + kt * 32 + kq;
                const float4 f0 = *(const float4*)ap;
                const float4 f1 = *(const float4*)(ap + 4);
                a[kt].u = make_uint4(pack2(f0.x, f0.y), pack2(f0.z, f0.w),
                                     pack2(f1.x, f1.y), pack2(f1.z, f1.w));
            } else {
                a[kt].u = *(const uint4*)(Ab + (size_t)arow * F + kt * 32 + kq);
            }
        } else {
            a[kt].u = make_uint4(0, 0, 0, 0);
        }
    }
    const int ccol = lane & 15;
    const int crow0 = m0 + ((lane >> 4) << 2);
    float rs[4] = {1.f, 1.f, 1.f, 1.f};
    if (row_scale) {
#pragma unroll
        for (int r = 0; r < 4; ++r) {
            const int row = crow0 + r;
            if (row < N) rs[r] = row_scale[row];
        }
    }
    float ps[4] = {}, pd[4] = {};
    for (int nt = 0; nt < 8; nt += 2) {
        float4v acc0 = {0.f, 0.f, 0.f, 0.f}, acc1 = {0.f, 0.f, 0.f, 0.f};
#pragma unroll
        for (int kt = 0; kt < 4; ++kt) {
            U8 b0, b1;
            b0.u = wf[(kt * 8 + nt) * 64 + lane];
            b1.u = wf[(kt * 8 + nt + 1) * 64 + lane];
            acc0 = __builtin_amdgcn_mfma_f32_16x16x32_bf16(a[kt].s, b0.s, acc0, 0, 0, 0);
            acc1 = __builtin_amdgcn_mfma_f32_16x16x32_bf16(a[kt].s, b1.s, acc1, 0, 0, 0);
        }
#pragma unroll
        for (int r = 0; r < 4; ++r) {
            const int row = crow0 + r;
            if (row < N) {
                Cb[(size_t)row * F + nt * 16 + ccol]       = (unsigned short)bf16rn(acc0[r] * rs[r]);
                Cb[(size_t)row * F + (nt + 1) * 16 + ccol] = (unsigned short)bf16rn(acc1[r] * rs[r]);
            }
        }
        if (asrc) {
            const float as0 = att_src[nt * 16 + ccol], as1 = att_src[(nt + 1) * 16 + ccol];
            const float ad0 = att_dst[nt * 16 + ccol], ad1 = att_dst[(nt + 1) * 16 + ccol];
#pragma unroll
            for (int r = 0; r < 4; ++r) {
                ps[r] += acc0[r] * as0 + acc1[r] * as1;
                pd[r] += acc0[r] * ad0 + acc1[r] * ad1;
            }
        }
    }
    if (asrc) {
#pragma unroll
        for (int r = 0; r < 4; ++r) {
            float s = ps[r], d = pd[r];
#pragma unroll
            for (int o = 8; o; o >>= 1) { s += __shfl_xor(s, o); d += __shfl_xor(d, o); }
            const int row = crow0 + r;
            if (ccol == 0 && row < N) { asrc[row] = s; adst[row] = d; }
        }
    }
}

// ---- Fused CSR bucket scatter: per-block LDS histogram -> one global range
// reservation per (bucket,block) -> scatter into fixed per-bucket regions.
__global__ void count_scatter(const int* __restrict__ ei, int* __restrict__ cur,
                              unsigned int* __restrict__ ebuf) {
    __shared__ int lcnt[NBUCK];
    __shared__ int lbase[NBUCK];
    const int t = threadIdx.x, b = blockIdx.x;
    for (int i = t; i < NBUCK; i += 256) lcnt[i] = 0;
    __syncthreads();
    const int e0 = b * EPB;
    int sarr[EPB / 256], darr[EPB / 256];
#pragma unroll
    for (int i = 0; i < EPB / 256; ++i) {
        const int e = e0 + i * 256 + t;
        int s = 0, d = -1;
        if (e < EP) {
            if (e < NE) { s = ei[e]; d = ei[NE + e]; } else { s = d = e - NE; }
            atomicAdd(&lcnt[d >> 8], 1);
        }
        sarr[i] = s; darr[i] = d;
    }
    __syncthreads();
    for (int i = t; i < NBUCK; i += 256) {
        lbase[i] = atomicAdd(&cur[i], lcnt[i]);   // reserve contiguous run
        lcnt[i] = 0;                              // reuse as local cursor
    }
    __syncthreads();
#pragma unroll
    for (int i = 0; i < EPB / 256; ++i) {
        const int d = darr[i];
        if (d >= 0) {
            const int bk = d >> 8;
            const int p = lbase[bk] + atomicAdd(&lcnt[bk], 1);
            ebuf[(size_t)bk * BCAP + p] = (unsigned int)sarr[i] | ((unsigned int)(d & 255) << 16);
        }
    }
}

// per-bucket LDS counting sort from fixed regions; emits row_start, deg, dinv,
// csr16 (fixed per-bucket regions: row_start[n] = g*BCAP + prefix).
__global__ void bucket_sort(const unsigned int* __restrict__ ebuf, const int* __restrict__ cnt,
                            int* __restrict__ row_start, unsigned short* __restrict__ csr16,
                            int* __restrict__ deg, float* __restrict__ dinv) {
    __shared__ unsigned int earr[BCAP];
    __shared__ unsigned short out16[BCAP];
    __shared__ int ecnt[256], epre[256];
    const int t = threadIdx.x, g = blockIdx.x;
    const int m = cnt[g];
    const unsigned int* src = ebuf + (size_t)g * BCAP;
    ecnt[t] = 0;
    __syncthreads();
    for (int i = t; i < m; i += 256) {
        const unsigned int v = src[i];
        earr[i] = v;
        atomicAdd(&ecnt[v >> 16], 1);
    }
    __syncthreads();
    const int v0 = ecnt[t];
    epre[t] = v0;
    __syncthreads();
    for (int o = 1; o < 256; o <<= 1) {
        const int u = (t >= o) ? epre[t - o] : 0;
        __syncthreads();
        epre[t] += u;
        __syncthreads();
    }
    const int my_excl = epre[t] - v0;
    const int n = g * 256 + t;
    if (n < NN) {
        row_start[n] = g * BCAP + my_excl;
        deg[n] = v0;                               // >= 1 (self loop)
        dinv[n] = rsqrtf((float)v0);
    }
    ecnt[t] = my_excl;
    __syncthreads();
    for (int i = t; i < m; i += 256) {
        const unsigned int v = earr[i];
        const int p = atomicAdd(&ecnt[v >> 16], 1);
        out16[p] = (unsigned short)(v & 0xffffu);
    }
    __syncthreads();
    unsigned short* dst = csr16 + (size_t)g * BCAP;
    for (int i = t; i < m; i += 256) dst[i] = out16[i];
}

// ---- GAT gather (R13-proven): one wave/node, 16 lanes/edge over 256B rows,
// 4 edges per issue group, dual accumulators.
__global__ void gat_gather(const int* __restrict__ row_start, const int* __restrict__ deg,
                           const unsigned short* __restrict__ csr_src,
                           const float* __restrict__ asrc, const float* __restrict__ adst,
                           const unsigned short* __restrict__ hb, const float* __restrict__ bias,
                           unsigned short* __restrict__ out) {
    const int n = blockIdx.x * 4 + (threadIdx.x >> 6);
    const int lane = threadIdx.x & 63;
    if (n >= NN) return;
    const int quarter = lane >> 4;
    const int qo = (lane & 15) << 3;
    const int lo = row_start[n], hi = lo + deg[n];
    const float adn = adst[n];
    float den = 0.f;
    float accA[8] = {}, accB[8] = {};
    for (int base = lo; base < hi; base += 64) {
        const int cnt = min(64, hi - base);
        const int sv = (lane < cnt) ? (int)csr_src[base + lane] : 0;
        float ev = 0.f;
        if (lane < cnt) {
            float sc = asrc[sv] + adn;
            sc = sc > 0.f ? sc : 0.2f * sc;
            ev = __expf(sc);
        }
        den += ev;
        int j = 0;
        for (; j + 16 <= cnt; j += 16) {
#pragma unroll
            for (int t = 0; t < 4; ++t) {
                const int jj = j + 4 * t + quarter;
                const int   s = __shfl(sv, jj);
                const float w = __shfl(ev, jj);
                const uint4 hv = *(const uint4*)(hb + (size_t)s * F + qo);
                bf8_fma((t & 1) ? accB : accA, w, hv);
            }
        }
        for (; j < cnt; j += 4) {       // jj <= 63; ev=0 pads beyond cnt
            const int jj = j + quarter;
            const int   s = __shfl(sv, jj);
            const float w = __shfl(ev, jj);
            const uint4 hv = *(const uint4*)(hb + (size_t)s * F + qo);
            bf8_fma(accA, w, hv);
        }
    }
    float acc[8];
#pragma unroll
    for (int i = 0; i < 8; ++i) {
        float v = accA[i] + accB[i];
        v += __shfl_xor(v, 16);
        v += __shfl_xor(v, 32);
        acc[i] = v;
    }
    for (int o = 32; o; o >>= 1) den += __shfl_xor(den, o);
    const float inv = 1.f / den;        // den > 0 (self loop)
    if (lane < 16) {
        float v[8];
#pragma unroll
        for (int i = 0; i < 8; ++i) {
            v[i] = fmaf(acc[i], inv, bias[qo + i]);
            v[i] = v[i] > 0.f ? v[i] : 0.f;
        }
        uint4 pk;
        pk.x = pack2(v[0], v[1]); pk.y = pack2(v[2], v[3]);
        pk.z = pack2(v[4], v[5]); pk.w = pack2(v[6], v[7]);
        *(uint4*)(out + (size_t)n * F + qo) = pk;
    }
}

// ---- GCN gather over pre-scaled rows (h2'[s] = dinv[s]*h2[s], scaled in
// gemm2's epilogue): no per-edge weight — shfl(src) -> row load -> add.
// Full 16-edge groups need no mask; remainder predicated on jj<cnt
// (quarter-uniform). Fused mean-pool/head partials unchanged.
__global__ void gcn_gather_pool(const int* __restrict__ row_start, const int* __restrict__ deg,
                                const unsigned short* __restrict__ csr_src,
                                const float* __restrict__ dinv, const unsigned short* __restrict__ hb,
                                const float* __restrict__ bias, const int* __restrict__ batch,
                                const float* __restrict__ Wf, float* __restrict__ gscr) {
    __shared__ int   sg[4];
    __shared__ float sp0[4], sp1[4];
    const int wave = threadIdx.x >> 6;
    const int n = blockIdx.x * 4 + wave;
    const int lane = threadIdx.x & 63;
    const int quarter = lane >> 4;
    const int qo = (lane & 15) << 3;
    if (threadIdx.x < 4) sg[threadIdx.x] = -1;
    float p0 = 0.f, p1 = 0.f;
    if (n < NN) {
        const int lo = row_start[n], hi = lo + deg[n];
        const float dn = dinv[n];
        float accA[8] = {}, accB[8] = {};
        for (int base = lo; base < hi; base += 64) {
            const int cnt = min(64, hi - base);
            const int sv = (lane < cnt) ? (int)csr_src[base + lane] : 0;
            int j = 0;
            for (; j + 16 <= cnt; j += 16) {
#pragma unroll
                for (int t = 0; t < 4; ++t) {
                    const int jj = j + 4 * t + quarter;
                    const int s = __shfl(sv, jj);
                    const uint4 hv = *(const uint4*)(hb + (size_t)s * F + qo);
                    bf8_add((t & 1) ? accB : accA, hv);
                }
            }
            for (; j < cnt; j += 4) {   // jj = j+quarter <= 63 (j mult of 4, j<cnt<=64)
                const int jj = j + quarter;
                const int s = __shfl(sv, jj);   // all lanes active
                if (jj < cnt) {
                    const uint4 hv = *(const uint4*)(hb + (size_t)s * F + qo);
                    bf8_add(accA, hv);
                }
            }
        }
        float v[8];
#pragma unroll
        for (int i = 0; i < 8; ++i) {
            float a = accA[i] + accB[i];
            a += __shfl_xor(a, 16);
            a += __shfl_xor(a, 32);
            v[i] = fmaf(a, dn, bias[qo + i]);
            v[i] = v[i] > 0.f ? v[i] : 0.f;
        }
        const float4 w0 = *(const float4*)(Wf + qo * 2);
        const float4 w1 = *(const float4*)(Wf + qo * 2 + 4);
        const float4 w2 = *(const float4*)(Wf + qo * 2 + 8);
        const float4 w3 = *(const float4*)(Wf + qo * 2 + 12);
        p0 = v[0]*w0.x + v[1]*w0.z + v[2]*w1.x + v[3]*w1.z +
             v[4]*w2.x + v[5]*w2.z + v[6]*w3.x + v[7]*w3.z;
        p1 = v[0]*w0.y + v[1]*w0.w + v[2]*w1.y + v[3]*w1.w +
             v[4]*w2.y + v[5]*w2.w + v[6]*w3.y + v[7]*w3.w;
        for (int o = 8; o; o >>= 1) { p0 += __shfl_xor(p0, o); p1 += __shfl_xor(p1, o); }
    }
    if (lane == 0 && n < NN) { sg[wave] = batch[n]; sp0[wave] = p0; sp1[wave] = p1; }
    __syncthreads();
    if (threadIdx.x == 0) {
#pragma unroll
        for (int w = 0; w < 4; ++w) {
            const int g = sg[w];
            if (g < 0) continue;
            float q0 = sp0[w], q1 = sp1[w];
            for (int u = w + 1; u < 4; ++u) {
                if (sg[u] == g) { q0 += sp0[u]; q1 += sp1[u]; sg[u] = -1; }
            }
            atomicAdd(gscr + g * 32,     q0);
            atomicAdd(gscr + g * 32 + 1, q1);
        }
    }
}

__global__ void finalize(const float* __restrict__ gscr, const int* __restrict__ batch,
                         const float* __restrict__ bf, float* __restrict__ out) {
    const int g = threadIdx.x;   // 128
    int lo = 0, hi = NN;
    while (lo < hi) { int m = (lo + hi) >> 1; if (batch[m] < g) lo = m + 1; else hi = m; }
    int lo2 = lo, hi2 = NN;
    while (lo2 < hi2) { int m = (lo2 + hi2) >> 1; if (batch[m] < g + 1) lo2 = m + 1; else hi2 = m; }
    const float inv = 1.f / fmaxf((float)(lo2 - lo), 1.f);
    out[g * 2]     = gscr[g * 32]     * inv + bf[0];
    out[g * 2 + 1] = gscr[g * 32 + 1] * inv + bf[1];
}

extern "C" void kernel_launch(void* const* d_in, const int* in_sizes, int n_in,
                              void* d_out, int out_size, void* d_ws, size_t ws_size,
                              hipStream_t stream) {
    const float* x       = (const float*)d_in[0];
    const float* W1      = (const float*)d_in[1];
    const float* att_src = (const float*)d_in[2];
    const float* att_dst = (const float*)d_in[3];
    const float* b1      = (const float*)d_in[4];
    const float* W2      = (const float*)d_in[5];
    const float* b2      = (const float*)d_in[6];
    const float* Wf      = (const float*)d_in[7];
    const float* bf      = (const float*)d_in[8];
    const int*   ei      = (const int*)d_in[9];
    const int*   batch   = (const int*)d_in[10];
    float* out = (float*)d_out;

    unsigned short* h1b  = (unsigned short*)d_ws;                   // [NN*F] bf16 gemm1 out
    unsigned short* hgb  = h1b + (size_t)NN * F;                    // [NN*F] bf16 GAT out
    unsigned short* h2b  = hgb + (size_t)NN * F;                    // [NN*F] bf16 gemm2 out (pre-scaled)
    float* asrc      = (float*)(h2b + (size_t)NN * F);              // [NN]
    float* adst      = asrc + NN;                                   // [NN]
    float* dinv      = adst + NN;                                   // [NN]
    float* gscr      = dinv + NN;                                   // [NG*32]
    int*   row_start = (int*)(gscr + NG * 32);                      // [NN]
    int*   deg       = row_start + NN;                              // [NN]
    int*   cnt       = deg + NN;                                    // [NBUCK]
    unsigned short* csr16 = (unsigned short*)(cnt + NBUCK);         // [NBUCK*BCAP]
    unsigned int*   ebuf  = (unsigned int*)(csr16 + (size_t)NBUCK * BCAP); // [NBUCK*BCAP]
    uint4* wf1       = (uint4*)(ebuf + (size_t)NBUCK * BCAP);       // [2048] W1 frags
    uint4* wf2       = wf1 + 2048;                                  // [2048] W2 frags

    // one-shot weight packing (+ gscr/cnt zeroing) + fused CSR build
    pack_wfrag2<<<17, 256, 0, stream>>>(W1, W2, wf1, gscr, cnt);
    count_scatter<<<NBE, 256, 0, stream>>>(ei, cnt, ebuf);
    bucket_sort<<<NBUCK, 256, 0, stream>>>(ebuf, cnt, row_start, csr16, deg, dinv);

    mfma_gemm<<<(NN + 63) / 64, 256, 0, stream>>>(nullptr, x, wf1, h1b, NN,
                                                  att_src, att_dst, asrc, adst, nullptr);
    gat_gather<<<(NN + 3) / 4, 256, 0, stream>>>(row_start, deg, csr16, asrc, adst,
                                                 h1b, b1, hgb);
    mfma_gemm<<<(NN + 63) / 64, 256, 0, stream>>>(hgb, nullptr, wf2, h2b, NN,
                                                  nullptr, nullptr, nullptr, nullptr, dinv);
    gcn_gather_pool<<<(NN + 3) / 4, 256, 0, stream>>>(row_start, deg, csr16, dinv, h2b, b2,
                                                      batch, Wf, gscr);
    finalize<<<1, NG, 0, stream>>>(gscr, batch, bf, out);
}